// Round 3
// baseline (902.266 us; speedup 1.0000x reference)
//
#include <hip/hip_runtime.h>
#include <math.h>

#define LMAXX 6
#define SH49 49
#define TPB 256
#define TILE_E 64
#define SCB 256
#define CAPS 24   // max distinct nodes per tile for LDS slot path

// ---------------------------------------------------------------------------
// bf16 pack/unpack helpers (RNE)
// ---------------------------------------------------------------------------
__device__ __forceinline__ unsigned pack_bf16(float a, float b) {
    unsigned ua = __float_as_uint(a);
    unsigned ub = __float_as_uint(b);
    ua += 0x7fffu + ((ua >> 16) & 1u);
    ub += 0x7fffu + ((ub >> 16) & 1u);
    return (ua >> 16) | (ub & 0xffff0000u);
}
__device__ __forceinline__ float bf16_lo(unsigned w) { return __uint_as_float(w << 16); }
__device__ __forceinline__ float bf16_hi(unsigned w) { return __uint_as_float(w & 0xffff0000u); }

// ---------------------------------------------------------------------------
// Real spherical harmonics up to l=6, 'component' normalization.
// ---------------------------------------------------------------------------
__device__ __forceinline__ void sph49(float x, float y, float z, float* sh) {
    float nn = sqrtf(x * x + y * y + z * z + 1e-12f);
    float iv = 1.0f / nn;
    x *= iv; y *= iv; z *= iv;
    float st2 = x * x + y * y;
    float st = sqrtf(st2 > 0.f ? st2 : 0.f);
    float cphi, sphi;
    if (st > 1e-30f) { cphi = x / st; sphi = y / st; }
    else { cphi = 1.0f; sphi = 0.0f; }

    float P[LMAXX + 1][LMAXX + 1];
    P[0][0] = 0.28209479177387814f;
#pragma unroll
    for (int m = 1; m <= LMAXX; ++m)
        P[m][m] = -sqrtf((2.f * m + 1.f) / (2.f * m)) * st * P[m - 1][m - 1];
#pragma unroll
    for (int m = 0; m < LMAXX; ++m)
        P[m + 1][m] = sqrtf(2.f * m + 3.f) * z * P[m][m];
#pragma unroll
    for (int m = 0; m <= LMAXX; ++m) {
#pragma unroll
        for (int l = m + 2; l <= LMAXX; ++l) {
            float a = sqrtf((4.f * l * l - 1.f) / (float)(l * l - m * m));
            float b = sqrtf((float)((l - 1) * (l - 1) - m * m) /
                            (4.f * (l - 1) * (l - 1) - 1.f));
            P[l][m] = a * (z * P[l - 1][m] - b * P[l - 2][m]);
        }
    }
    float cm[LMAXX + 1], sm[LMAXX + 1];
    cm[0] = 1.f; sm[0] = 0.f; cm[1] = cphi; sm[1] = sphi;
#pragma unroll
    for (int m = 2; m <= LMAXX; ++m) {
        cm[m] = 2.f * cphi * cm[m - 1] - cm[m - 2];
        sm[m] = 2.f * cphi * sm[m - 1] - sm[m - 2];
    }
    const float s4pi = 3.5449077018110318f;
    const float s8pi = 5.0132565492620005f;
    int idx = 0;
#pragma unroll
    for (int l = 0; l <= LMAXX; ++l) {
#pragma unroll
        for (int mm = -l; mm <= l; ++mm) {
            if (mm < 0)       sh[idx++] = s8pi * P[l][-mm] * sm[-mm];
            else if (mm == 0) sh[idx++] = s4pi * P[l][0];
            else              sh[idx++] = s8pi * P[l][mm] * cm[mm];
        }
    }
}

// ---------------------------------------------------------------------------
// K1: destination-degree histogram (int atomics only).
// ---------------------------------------------------------------------------
__global__ void k_hist(const int* __restrict__ eidx, int* __restrict__ icnt, int E) {
    int e = blockIdx.x * blockDim.x + threadIdx.x;
    if (e >= E) return;
    atomicAdd(&icnt[eidx[E + e]], 1);
}

// ---------------------------------------------------------------------------
// Counting-sort scan kernels: exclusive prefix over icnt[N].
// ---------------------------------------------------------------------------
__global__ void k_scan1(const int* __restrict__ icnt, int* __restrict__ offs,
                        int* __restrict__ bsum, int N) {
    __shared__ int s[SCB];
    int t = threadIdx.x;
    int idx = blockIdx.x * SCB + t;
    int v = (idx < N) ? icnt[idx] : 0;
    s[t] = v; __syncthreads();
#pragma unroll
    for (int off = 1; off < SCB; off <<= 1) {
        int u = (t >= off) ? s[t - off] : 0;
        __syncthreads();
        s[t] += u;
        __syncthreads();
    }
    if (idx < N) offs[idx] = s[t] - v;
    if (t == SCB - 1) bsum[blockIdx.x] = s[t];
}

__global__ void k_scan2(int* __restrict__ bsum, int nb) {
    __shared__ int s[1024];
    int t = threadIdx.x;
    int v = (t < nb) ? bsum[t] : 0;
    s[t] = v; __syncthreads();
#pragma unroll
    for (int off = 1; off < 1024; off <<= 1) {
        int u = (t >= off) ? s[t - off] : 0;
        __syncthreads();
        s[t] += u;
        __syncthreads();
    }
    if (t < nb) bsum[t] = s[t] - v;
}

__global__ void k_scan3(int* __restrict__ offs, const int* __restrict__ bsum,
                        int* __restrict__ cursor, int N) {
    int idx = blockIdx.x * SCB + threadIdx.x;
    if (idx >= N) return;
    int o = offs[idx] + bsum[blockIdx.x];
    offs[idx] = o;
    cursor[idx] = o;
}

// ---------------------------------------------------------------------------
// K2: build permutation + scatter edge data into sorted (by dest i) order.
// ---------------------------------------------------------------------------
__global__ void k_perm(const float* __restrict__ ud, const int* __restrict__ eidx,
                       int* __restrict__ cursor, int* __restrict__ perm,
                       int* __restrict__ ii_s, int* __restrict__ jj_s,
                       float* __restrict__ ud_s, int E) {
    int e = blockIdx.x * blockDim.x + threadIdx.x;
    if (e >= E) return;
    int i = eidx[E + e];
    int j = eidx[e];
    int pos = atomicAdd(&cursor[i], 1);
    perm[pos] = e;
    ii_s[pos] = i;
    jj_s[pos] = j;
    ud_s[3 * pos + 0] = ud[3 * e + 0];
    ud_s[3 * pos + 1] = ud[3 * e + 1];
    ud_s[3 * pos + 2] = ud[3 * e + 2];
}

// ---------------------------------------------------------------------------
// K3: per-node ref_vec via CSR segment sum (no atomics) + ref SH.
// ---------------------------------------------------------------------------
__global__ void k_node_ref(const int* __restrict__ offs, const int* __restrict__ icnt,
                           const float* __restrict__ ud_s,
                           float* __restrict__ ref_vec, float* __restrict__ ref_sh,
                           int N) {
    int n = blockIdx.x * blockDim.x + threadIdx.x;
    if (n >= N) return;
    int o0 = offs[n], c = icnt[n];
    float sx = 0.f, sy = 0.f, sz = 0.f;
    for (int e = o0; e < o0 + c; ++e) {
        sx += ud_s[3 * e + 0];
        sy += ud_s[3 * e + 1];
        sz += ud_s[3 * e + 2];
    }
    float d = fmaxf((float)c, 1.0f);
    float vx = sx / d, vy = sy / d, vz = sz / d;
    float norm = sqrtf(vx * vx + vy * vy + vz * vz + 1e-9f);
    float ivn = 1.0f / norm;
    vx *= ivn; vy *= ivn; vz *= ivn;
    if (norm < 5e-5f) { vx = 1.f; vy = 0.f; vz = 0.f; }
    ref_vec[3 * n + 0] = vx;
    ref_vec[3 * n + 1] = vy;
    ref_vec[3 * n + 2] = vz;
    sph49(vx, vy, vz, ref_sh + (size_t)n * SH49);
}

// ---------------------------------------------------------------------------
// K4: scalar_proj, written bf16-PACKED: word w = oc+32q packs cols
// (64q+oc, 64q+oc+32) of the 192-wide row.
// ---------------------------------------------------------------------------
__global__ __launch_bounds__(TPB) void k_sproj(const float* __restrict__ ns,
                                               const float* __restrict__ W1,
                                               const float* __restrict__ b1,
                                               const float* __restrict__ W2,
                                               const float* __restrict__ b2,
                                               unsigned* __restrict__ spj_p, int N) {
    __shared__ float sW1[64 * 32];
    __shared__ float sW2[32 * 192];
    __shared__ float sb2[192];
    __shared__ float sb1[32];
    __shared__ float sbuf[4][64];
    __shared__ float h1buf[4][32];
    __shared__ float srow[4][192];
    int t = threadIdx.x;
    for (int p = t; p < 64 * 32; p += TPB) sW1[p] = W1[p];
    for (int p = t; p < 32 * 192; p += TPB) sW2[p] = W2[p];
    if (t < 192) sb2[t] = b2[t];
    if (t < 32) sb1[t] = b1[t];

    int w = t >> 6, l = t & 63;
    int nwaves = gridDim.x * 4;
    int iters = (N + nwaves - 1) / nwaves;
    for (int it = 0; it < iters; ++it) {
        int n = blockIdx.x * 4 + w + it * nwaves;
        bool act = n < N;
        __syncthreads();
        if (act) sbuf[w][l] = ns[(size_t)n * 64 + l];
        __syncthreads();
        if (act) {
            int k = l & 31;
            float h = sb1[k];
#pragma unroll
            for (int c = 0; c < 64; ++c) h = fmaf(sbuf[w][c], sW1[c * 32 + k], h);
            float sig = 1.0f / (1.0f + __expf(-h));
            h = h * sig * (1.0f / 0.6f);
            if (l < 32) h1buf[w][l] = h;
        }
        __syncthreads();
        if (act) {
#pragma unroll
            for (int m = 0; m < 3; ++m) {
                int o = l + 64 * m;
                float a = sb2[o];
#pragma unroll
                for (int kk = 0; kk < 32; ++kk)
                    a = fmaf(h1buf[w][kk], sW2[kk * 192 + o], a);
                srow[w][o] = a;
            }
        }
        __syncthreads();
        if (act) {
            // pack 96 words: lane l does word l; lanes <32 also word 64+l
            {
                int ww = l;
                if (ww < 96) {
                    int oc = ww & 31, q = ww >> 5;
                    spj_p[(size_t)n * 96 + ww] =
                        pack_bf16(srow[w][64 * q + oc], srow[w][64 * q + oc + 32]);
                }
            }
            if (l < 32) {
                int ww = 64 + l;
                int oc = ww & 31, q = ww >> 5;
                spj_p[(size_t)n * 96 + ww] =
                    pack_bf16(srow[w][64 * q + oc], srow[w][64 * q + oc + 32]);
            }
        }
    }
}

// ---------------------------------------------------------------------------
// K5: pack node_vector to bf16 pairs: word w = 32d+oc packs (192-row cols
// d*64+oc, d*64+oc+32).
// ---------------------------------------------------------------------------
__global__ void k_nvp(const float* __restrict__ nvec, unsigned* __restrict__ nvp,
                      int total /* N*96 */) {
    int idx = blockIdx.x * blockDim.x + threadIdx.x;
    if (idx >= total) return;
    int n = idx / 96, w = idx - n * 96;
    int d = w >> 5, oc = w & 31;
    size_t base = (size_t)n * 192 + d * 64 + oc;
    nvp[idx] = pack_bf16(nvec[base], nvec[base + 32]);
}

// ---------------------------------------------------------------------------
// K6: geometry features in sorted order (all coalesced now).
// ---------------------------------------------------------------------------
__global__ void k_geom_s(const float* __restrict__ ud_s, const int* __restrict__ ii_s,
                         const float* __restrict__ ref_vec,
                         const float* __restrict__ ref_sh,
                         const float* __restrict__ ln_g, const float* __restrict__ ln_b,
                         float* __restrict__ geom_s, int E) {
    int r = blockIdx.x * blockDim.x + threadIdx.x;
    if (r >= E) return;
    int i = ii_s[r];
    float ux = ud_s[3 * r], uy = ud_s[3 * r + 1], uz = ud_s[3 * r + 2];
    float esh[SH49];
    sph49(ux, uy, uz, esh);
    const float* rs = ref_sh + (size_t)i * SH49;
    float inv[7];
    int idx = 0;
#pragma unroll
    for (int l = 0; l <= 6; ++l) {
        float s = 0.f;
#pragma unroll
        for (int m = 0; m < 2 * l + 1; ++m) { s += esh[idx] * rs[idx]; idx++; }
        inv[l] = s / (float)(2 * l + 1);
    }
    float mu = 0.f;
#pragma unroll
    for (int l = 0; l < 7; ++l) mu += inv[l];
    mu *= (1.0f / 7.0f);
    float var = 0.f;
#pragma unroll
    for (int l = 0; l < 7; ++l) { float d = inv[l] - mu; var += d * d; }
    var *= (1.0f / 7.0f);
    float rstd = rsqrtf(var + 1e-5f);
    float rvx = ref_vec[3 * i], rvy = ref_vec[3 * i + 1], rvz = ref_vec[3 * i + 2];
    float ct = ux * rvx + uy * rvy + uz * rvz;
    float* g = geom_s + (size_t)r * 8;
    g[0] = ct;
#pragma unroll
    for (int l = 0; l < 7; ++l) g[1 + l] = (inv[l] - mu) * rstd * ln_g[l] + ln_b[l];
}

// ---------------------------------------------------------------------------
// K7: fused main kernel over sorted edges with per-tile LDS slot reduction.
// ---------------------------------------------------------------------------
__global__ __launch_bounds__(TPB, 2) void k_main(
    const float* __restrict__ rbf, const float* __restrict__ W_edge,
    const float* __restrict__ b_edge, const float* __restrict__ W_inv,
    const float* __restrict__ b_inv, const float* __restrict__ geom_s,
    const unsigned* __restrict__ spj_p, const unsigned* __restrict__ nvp,
    const float* __restrict__ ud_s, const int* __restrict__ ii_s,
    const int* __restrict__ jj_s, const int* __restrict__ perm,
    float* __restrict__ dscal, float* __restrict__ dvec, int E) {
    __shared__ unsigned sWp[64 * 96];    // 24.0 KB  bf16-pair packed W_edge
    __shared__ float sWinv[8 * 192];     // 6.0 KB
    __shared__ float sbe[192];
    __shared__ float sbi[192];
    __shared__ float rbfT[64 * 68];      // 17.0 KB  [k][edge]
    __shared__ float sgeom[64 * 8];
    __shared__ float sud[64 * 3];
    __shared__ int sii[64];
    __shared__ int sjj[64];
    __shared__ int sslot[64];
    __shared__ int sfirst[64];
    __shared__ int sD;
    __shared__ float sacc[CAPS * 256];   // 24.0 KB  slot accumulators

    int t = threadIdx.x;
    for (int p = t; p < 64 * 96; p += TPB) {
        int k = p / 96, w = p - k * 96;
        int oc = w & 31, q = w >> 5;
        sWp[p] = pack_bf16(W_edge[k * 192 + 64 * q + oc],
                           W_edge[k * 192 + 64 * q + oc + 32]);
    }
    for (int p = t; p < 8 * 192; p += TPB) sWinv[p] = W_inv[p];
    if (t < 192) { sbe[t] = b_edge[t]; sbi[t] = b_inv[t]; }

    int oc = t & 31;
    int er = t >> 5;  // 0..7
    const float inv_sqrt3 = 0.57735026918962584f;
    const float inv_sqrt_h = 0.125f;

    int ntiles = (E + TILE_E - 1) / TILE_E;
    for (int tile = blockIdx.x; tile < ntiles; tile += gridDim.x) {
        int e0 = tile * TILE_E;
        __syncthreads();   // (A) prior flush done before restage
        if (t < 64) {
            int rg = e0 + t;
            sjj[t] = (rg < E) ? jj_s[rg] : 0;
            sii[t] = (rg < E) ? ii_s[rg] : -1;
        }
        for (int p = t; p < 64 * 8; p += TPB)
            sgeom[p] = (e0 + (p >> 3) < E) ? geom_s[(size_t)e0 * 8 + p] : 0.f;
        for (int p = t; p < 64 * 3; p += TPB)
            sud[p] = (e0 + p / 3 < E) ? ud_s[(size_t)e0 * 3 + p] : 0.f;
        {
            int w = t >> 6, l = t & 63;
#pragma unroll
            for (int p = 0; p < 16; ++p) {
                int r = w + 4 * p;
                int rg = e0 + r;
                float v = 0.f;
                if (rg < E) {
                    int eg = perm[rg];
                    v = rbf[(size_t)eg * 64 + l];
                }
                rbfT[l * 68 + r] = v;
            }
        }
        __syncthreads();   // (B)

        // wave 0: node-boundary ballot scan -> slots
        if (t < 64) {
            bool flag = (t == 0) || (sii[t] != sii[t - 1]);
            unsigned long long bal = __ballot(flag);
            unsigned long long mask =
                (t == 63) ? ~0ull : ((1ull << (t + 1)) - 1ull);
            int slot = __popcll(bal & mask) - 1;
            sslot[t] = slot;
            if (flag) sfirst[slot] = t;
            if (t == 0) sD = __popcll(bal);
        }

        // ---- GEMM: acc[e][m] = sum_k rbf[e][k] * W[k][oc+32m] ----
        float acc[8][6];
#pragma unroll
        for (int e = 0; e < 8; ++e)
#pragma unroll
            for (int m = 0; m < 6; ++m) acc[e][m] = 0.f;

        const float* rb = &rbfT[er * 8];
#pragma unroll 4
        for (int k = 0; k < 64; ++k) {
            float4 r0 = *(const float4*)&rb[k * 68];
            float4 r1 = *(const float4*)&rb[k * 68 + 4];
            unsigned w0 = sWp[k * 96 + oc];
            unsigned w1 = sWp[k * 96 + oc + 32];
            unsigned w2 = sWp[k * 96 + oc + 64];
            float wv[6] = {bf16_lo(w0), bf16_hi(w0), bf16_lo(w1),
                           bf16_hi(w1), bf16_lo(w2), bf16_hi(w2)};
            float re[8] = {r0.x, r0.y, r0.z, r0.w, r1.x, r1.y, r1.z, r1.w};
#pragma unroll
            for (int e = 0; e < 8; ++e)
#pragma unroll
                for (int m = 0; m < 6; ++m)
                    acc[e][m] = fmaf(re[e], wv[m], acc[e][m]);
        }

        __syncthreads();   // (C) scan results visible; GEMM done
        int D = sD;
        bool slotmode = (D <= CAPS);
        if (slotmode) {
            for (int p = t; p < D * 256; p += TPB) sacc[p] = 0.f;
        }
        __syncthreads();   // (D) sacc zeroed before atomics

        // ---- epilogue: gate + scale, run-accumulate, flush to LDS/global ----
        float a_s0 = 0.f, a_s1 = 0.f;
        float a_v[3][2] = {{0.f, 0.f}, {0.f, 0.f}, {0.f, 0.f}};
        int runi = -1, runslot = -1;
        bool any = false;
#pragma unroll 1
        for (int e = 0; e < 8; ++e) {
            int el = er * 8 + e;
            int rg = e0 + el;
            if (rg >= E) break;
            int j = sjj[el], i = sii[el];
            if (i != runi) {
                if (any) {
                    if (slotmode) {
                        float* sa = &sacc[runslot * 256];
                        atomicAdd(&sa[oc], a_s0);
                        atomicAdd(&sa[oc + 32], a_s1);
#pragma unroll
                        for (int d = 0; d < 3; ++d) {
                            atomicAdd(&sa[64 + d * 64 + oc], a_v[d][0]);
                            atomicAdd(&sa[64 + d * 64 + oc + 32], a_v[d][1]);
                        }
                    } else {
                        atomicAdd(&dscal[(size_t)runi * 64 + oc], a_s0);
                        atomicAdd(&dscal[(size_t)runi * 64 + oc + 32], a_s1);
#pragma unroll
                        for (int d = 0; d < 3; ++d) {
                            atomicAdd(&dvec[(size_t)runi * 192 + d * 64 + oc], a_v[d][0]);
                            atomicAdd(&dvec[(size_t)runi * 192 + d * 64 + oc + 32], a_v[d][1]);
                        }
                    }
                }
                a_s0 = 0.f; a_s1 = 0.f;
#pragma unroll
                for (int d = 0; d < 3; ++d) { a_v[d][0] = 0.f; a_v[d][1] = 0.f; }
                runi = i; runslot = sslot[el];
            }
            any = true;
            // gathers (bf16-packed rows, 3 dwords each)
            unsigned sp0 = spj_p[(size_t)j * 96 + oc];
            unsigned sp1 = spj_p[(size_t)j * 96 + oc + 32];
            unsigned sp2 = spj_p[(size_t)j * 96 + oc + 64];
            unsigned nv0 = nvp[(size_t)j * 96 + oc];
            unsigned nv1 = nvp[(size_t)j * 96 + oc + 32];
            unsigned nv2 = nvp[(size_t)j * 96 + oc + 64];
            float sp[6] = {bf16_lo(sp0), bf16_hi(sp0), bf16_lo(sp1),
                           bf16_hi(sp1), bf16_lo(sp2), bf16_hi(sp2)};
            float x[6];
#pragma unroll
            for (int m = 0; m < 6; ++m) {
                int o = oc + 32 * m;
                float u = sbi[o];
#pragma unroll
                for (int c = 0; c < 8; ++c)
                    u = fmaf(sgeom[el * 8 + c], sWinv[c * 192 + o], u);
                float sig = 1.0f / (1.0f + __expf(-u));
                float v = u * sig * (1.0f / 0.6f);
                v = fminf(fmaxf(v, -20.f), 20.f);
                float e2v = __expf(2.0f * v);
                float gate = (e2v - 1.0f) / (e2v + 1.0f);
                float rh = (acc[e][m] + sbe[o]) * (1.0f + gate);
                x[m] = sp[m] * rh * inv_sqrt3;
            }
            a_s0 += x[4];
            a_s1 += x[5];
            float udv[3] = {sud[el * 3], sud[el * 3 + 1], sud[el * 3 + 2]};
            unsigned nw[3] = {nv0, nv1, nv2};
#pragma unroll
            for (int d = 0; d < 3; ++d) {
                a_v[d][0] += (x[0] * bf16_lo(nw[d]) + x[2] * udv[d]) * inv_sqrt_h;
                a_v[d][1] += (x[1] * bf16_hi(nw[d]) + x[3] * udv[d]) * inv_sqrt_h;
            }
        }
        if (any) {
            if (slotmode) {
                float* sa = &sacc[runslot * 256];
                atomicAdd(&sa[oc], a_s0);
                atomicAdd(&sa[oc + 32], a_s1);
#pragma unroll
                for (int d = 0; d < 3; ++d) {
                    atomicAdd(&sa[64 + d * 64 + oc], a_v[d][0]);
                    atomicAdd(&sa[64 + d * 64 + oc + 32], a_v[d][1]);
                }
            } else {
                atomicAdd(&dscal[(size_t)runi * 64 + oc], a_s0);
                atomicAdd(&dscal[(size_t)runi * 64 + oc + 32], a_s1);
#pragma unroll
                for (int d = 0; d < 3; ++d) {
                    atomicAdd(&dvec[(size_t)runi * 192 + d * 64 + oc], a_v[d][0]);
                    atomicAdd(&dvec[(size_t)runi * 192 + d * 64 + oc + 32], a_v[d][1]);
                }
            }
        }
        __syncthreads();   // (E) all LDS atomics done

        // ---- flush slots: interior = plain store, boundary = atomic ----
        if (slotmode) {
            int Dreal = D - ((sii[63] < 0) ? 1 : 0);
            for (int s = 0; s < D; ++s) {
                int n = sii[sfirst[s]];
                if (n < 0) continue;
                float val = sacc[s * 256 + t];
                bool boundary = (s == 0) || (s == Dreal - 1);
                float* ptr = (t < 64) ? &dscal[(size_t)n * 64 + t]
                                      : &dvec[(size_t)n * 192 + (t - 64)];
                if (boundary) atomicAdd(ptr, val);
                else *ptr = val;
            }
        }
    }
}

// ---------------------------------------------------------------------------
extern "C" void kernel_launch(void* const* d_in, const int* in_sizes, int n_in,
                              void* d_out, int out_size, void* d_ws, size_t ws_size,
                              hipStream_t stream) {
    const float* node_scalar = (const float*)d_in[0];
    const float* node_vector = (const float*)d_in[1];
    const float* edge_rbf    = (const float*)d_in[2];
    const float* edge_udiff  = (const float*)d_in[3];
    const int*   edge_index  = (const int*)d_in[4];
    const float* W_edge      = (const float*)d_in[5];
    const float* b_edge      = (const float*)d_in[6];
    const float* W_x1        = (const float*)d_in[7];
    const float* b_x1        = (const float*)d_in[8];
    const float* W_x2        = (const float*)d_in[9];
    const float* b_x2        = (const float*)d_in[10];
    const float* ln_g        = (const float*)d_in[11];
    const float* ln_b        = (const float*)d_in[12];
    const float* W_inv       = (const float*)d_in[13];
    const float* b_inv       = (const float*)d_in[14];

    int N = in_sizes[0] / 64;
    int E = in_sizes[3] / 3;

    float* ws = (float*)d_ws;
    size_t o = 0;
    int*      icnt   = (int*)(ws + o); o += N;
    int*      offs   = (int*)(ws + o); o += N;
    int*      cursor = (int*)(ws + o); o += N;
    int*      bsum   = (int*)(ws + o); o += 1024;
    float*    ref_vec= ws + o; o += (size_t)N * 3;
    float*    ref_sh = ws + o; o += (size_t)N * SH49;
    unsigned* spj_p  = (unsigned*)(ws + o); o += (size_t)N * 96;
    unsigned* nvp    = (unsigned*)(ws + o); o += (size_t)N * 96;
    int*      perm   = (int*)(ws + o); o += E;
    float*    geom_s = ws + o; o += (size_t)E * 8;
    float*    ud_s   = ws + o; o += (size_t)E * 3;
    int*      ii_s   = (int*)(ws + o); o += E;
    int*      jj_s   = (int*)(ws + o); o += E;

    float* dscal = (float*)d_out;                       // N*64
    float* dvec  = (float*)d_out + (size_t)N * 64;      // N*192

    hipMemsetAsync(icnt, 0, (size_t)N * sizeof(int), stream);
    hipMemsetAsync(d_out, 0, (size_t)out_size * sizeof(float), stream);

    int nb = (N + SCB - 1) / SCB;

    k_hist<<<(E + TPB - 1) / TPB, TPB, 0, stream>>>(edge_index, icnt, E);
    k_scan1<<<nb, SCB, 0, stream>>>(icnt, offs, bsum, N);
    k_scan2<<<1, 1024, 0, stream>>>(bsum, nb);
    k_scan3<<<nb, SCB, 0, stream>>>(offs, bsum, cursor, N);
    k_perm<<<(E + TPB - 1) / TPB, TPB, 0, stream>>>(edge_udiff, edge_index, cursor,
                                                    perm, ii_s, jj_s, ud_s, E);
    k_node_ref<<<(N + TPB - 1) / TPB, TPB, 0, stream>>>(offs, icnt, ud_s,
                                                        ref_vec, ref_sh, N);
    k_sproj<<<512, TPB, 0, stream>>>(node_scalar, W_x1, b_x1, W_x2, b_x2, spj_p, N);
    k_nvp<<<(N * 96 + TPB - 1) / TPB, TPB, 0, stream>>>(node_vector, nvp, N * 96);
    k_geom_s<<<(E + TPB - 1) / TPB, TPB, 0, stream>>>(ud_s, ii_s, ref_vec, ref_sh,
                                                      ln_g, ln_b, geom_s, E);
    k_main<<<512, TPB, 0, stream>>>(edge_rbf, W_edge, b_edge, W_inv, b_inv, geom_s,
                                    spj_p, nvp, ud_s, ii_s, jj_s, perm,
                                    dscal, dvec, E);
}

// Round 4
// 790.874 us; speedup vs baseline: 1.1408x; 1.1408x over previous
//
#include <hip/hip_runtime.h>
#include <math.h>

#define LMAXX 6
#define SH49 49
#define TPB 256
#define TILE_E 64
#define SCB 256
#define CAPS 24   // max distinct nodes per tile for LDS slot path

// ---------------------------------------------------------------------------
// bf16 pack/unpack helpers (RNE)
// ---------------------------------------------------------------------------
__device__ __forceinline__ unsigned pack_bf16(float a, float b) {
    unsigned ua = __float_as_uint(a);
    unsigned ub = __float_as_uint(b);
    ua += 0x7fffu + ((ua >> 16) & 1u);
    ub += 0x7fffu + ((ub >> 16) & 1u);
    return (ua >> 16) | (ub & 0xffff0000u);
}
__device__ __forceinline__ float bf16_lo(unsigned w) { return __uint_as_float(w << 16); }
__device__ __forceinline__ float bf16_hi(unsigned w) { return __uint_as_float(w & 0xffff0000u); }

// ---------------------------------------------------------------------------
// Real spherical harmonics up to l=6, 'component' normalization.
// ---------------------------------------------------------------------------
__device__ __forceinline__ void sph49(float x, float y, float z, float* sh) {
    float nn = sqrtf(x * x + y * y + z * z + 1e-12f);
    float iv = 1.0f / nn;
    x *= iv; y *= iv; z *= iv;
    float st2 = x * x + y * y;
    float st = sqrtf(st2 > 0.f ? st2 : 0.f);
    float cphi, sphi;
    if (st > 1e-30f) { cphi = x / st; sphi = y / st; }
    else { cphi = 1.0f; sphi = 0.0f; }

    float P[LMAXX + 1][LMAXX + 1];
    P[0][0] = 0.28209479177387814f;
#pragma unroll
    for (int m = 1; m <= LMAXX; ++m)
        P[m][m] = -sqrtf((2.f * m + 1.f) / (2.f * m)) * st * P[m - 1][m - 1];
#pragma unroll
    for (int m = 0; m < LMAXX; ++m)
        P[m + 1][m] = sqrtf(2.f * m + 3.f) * z * P[m][m];
#pragma unroll
    for (int m = 0; m <= LMAXX; ++m) {
#pragma unroll
        for (int l = m + 2; l <= LMAXX; ++l) {
            float a = sqrtf((4.f * l * l - 1.f) / (float)(l * l - m * m));
            float b = sqrtf((float)((l - 1) * (l - 1) - m * m) /
                            (4.f * (l - 1) * (l - 1) - 1.f));
            P[l][m] = a * (z * P[l - 1][m] - b * P[l - 2][m]);
        }
    }
    float cm[LMAXX + 1], sm[LMAXX + 1];
    cm[0] = 1.f; sm[0] = 0.f; cm[1] = cphi; sm[1] = sphi;
#pragma unroll
    for (int m = 2; m <= LMAXX; ++m) {
        cm[m] = 2.f * cphi * cm[m - 1] - cm[m - 2];
        sm[m] = 2.f * cphi * sm[m - 1] - sm[m - 2];
    }
    const float s4pi = 3.5449077018110318f;
    const float s8pi = 5.0132565492620005f;
    int idx = 0;
#pragma unroll
    for (int l = 0; l <= LMAXX; ++l) {
#pragma unroll
        for (int mm = -l; mm <= l; ++mm) {
            if (mm < 0)       sh[idx++] = s8pi * P[l][-mm] * sm[-mm];
            else if (mm == 0) sh[idx++] = s4pi * P[l][0];
            else              sh[idx++] = s8pi * P[l][mm] * cm[mm];
        }
    }
}

// ---------------------------------------------------------------------------
// K1: destination-degree histogram (int atomics only).
// ---------------------------------------------------------------------------
__global__ void k_hist(const int* __restrict__ eidx, int* __restrict__ icnt, int E) {
    int e = blockIdx.x * blockDim.x + threadIdx.x;
    if (e >= E) return;
    atomicAdd(&icnt[eidx[E + e]], 1);
}

// ---------------------------------------------------------------------------
// Counting-sort scan kernels: exclusive prefix over icnt[N].
// ---------------------------------------------------------------------------
__global__ void k_scan1(const int* __restrict__ icnt, int* __restrict__ offs,
                        int* __restrict__ bsum, int N) {
    __shared__ int s[SCB];
    int t = threadIdx.x;
    int idx = blockIdx.x * SCB + t;
    int v = (idx < N) ? icnt[idx] : 0;
    s[t] = v; __syncthreads();
#pragma unroll
    for (int off = 1; off < SCB; off <<= 1) {
        int u = (t >= off) ? s[t - off] : 0;
        __syncthreads();
        s[t] += u;
        __syncthreads();
    }
    if (idx < N) offs[idx] = s[t] - v;
    if (t == SCB - 1) bsum[blockIdx.x] = s[t];
}

__global__ void k_scan2(int* __restrict__ bsum, int nb) {
    __shared__ int s[1024];
    int t = threadIdx.x;
    int v = (t < nb) ? bsum[t] : 0;
    s[t] = v; __syncthreads();
#pragma unroll
    for (int off = 1; off < 1024; off <<= 1) {
        int u = (t >= off) ? s[t - off] : 0;
        __syncthreads();
        s[t] += u;
        __syncthreads();
    }
    if (t < nb) bsum[t] = s[t] - v;
}

__global__ void k_scan3(int* __restrict__ offs, const int* __restrict__ bsum,
                        int* __restrict__ cursor, int N) {
    int idx = blockIdx.x * SCB + threadIdx.x;
    if (idx >= N) return;
    int o = offs[idx] + bsum[blockIdx.x];
    offs[idx] = o;
    cursor[idx] = o;
}

// ---------------------------------------------------------------------------
// K2: build permutation + scatter edge data into sorted (by dest i) order.
// ---------------------------------------------------------------------------
__global__ void k_perm(const float* __restrict__ ud, const int* __restrict__ eidx,
                       int* __restrict__ cursor, int* __restrict__ perm,
                       int* __restrict__ ii_s, int* __restrict__ jj_s,
                       float* __restrict__ ud_s, int E) {
    int e = blockIdx.x * blockDim.x + threadIdx.x;
    if (e >= E) return;
    int i = eidx[E + e];
    int j = eidx[e];
    int pos = atomicAdd(&cursor[i], 1);
    perm[pos] = e;
    ii_s[pos] = i;
    jj_s[pos] = j;
    ud_s[3 * pos + 0] = ud[3 * e + 0];
    ud_s[3 * pos + 1] = ud[3 * e + 1];
    ud_s[3 * pos + 2] = ud[3 * e + 2];
}

// ---------------------------------------------------------------------------
// K3: per-node ref_vec via CSR segment sum (no atomics) + ref SH.
// ---------------------------------------------------------------------------
__global__ void k_node_ref(const int* __restrict__ offs, const int* __restrict__ icnt,
                           const float* __restrict__ ud_s,
                           float* __restrict__ ref_vec, float* __restrict__ ref_sh,
                           int N) {
    int n = blockIdx.x * blockDim.x + threadIdx.x;
    if (n >= N) return;
    int o0 = offs[n], c = icnt[n];
    float sx = 0.f, sy = 0.f, sz = 0.f;
    for (int e = o0; e < o0 + c; ++e) {
        sx += ud_s[3 * e + 0];
        sy += ud_s[3 * e + 1];
        sz += ud_s[3 * e + 2];
    }
    float d = fmaxf((float)c, 1.0f);
    float vx = sx / d, vy = sy / d, vz = sz / d;
    float norm = sqrtf(vx * vx + vy * vy + vz * vz + 1e-9f);
    float ivn = 1.0f / norm;
    vx *= ivn; vy *= ivn; vz *= ivn;
    if (norm < 5e-5f) { vx = 1.f; vy = 0.f; vz = 0.f; }
    ref_vec[3 * n + 0] = vx;
    ref_vec[3 * n + 1] = vy;
    ref_vec[3 * n + 2] = vz;
    sph49(vx, vy, vz, ref_sh + (size_t)n * SH49);
}

// ---------------------------------------------------------------------------
// K4: scalar_proj, written bf16-PACKED: word w = oc+32q packs cols
// (64q+oc, 64q+oc+32) of the 192-wide row.
// ---------------------------------------------------------------------------
__global__ __launch_bounds__(TPB) void k_sproj(const float* __restrict__ ns,
                                               const float* __restrict__ W1,
                                               const float* __restrict__ b1,
                                               const float* __restrict__ W2,
                                               const float* __restrict__ b2,
                                               unsigned* __restrict__ spj_p, int N) {
    __shared__ float sW1[64 * 32];
    __shared__ float sW2[32 * 192];
    __shared__ float sb2[192];
    __shared__ float sb1[32];
    __shared__ float sbuf[4][64];
    __shared__ float h1buf[4][32];
    __shared__ float srow[4][192];
    int t = threadIdx.x;
    for (int p = t; p < 64 * 32; p += TPB) sW1[p] = W1[p];
    for (int p = t; p < 32 * 192; p += TPB) sW2[p] = W2[p];
    if (t < 192) sb2[t] = b2[t];
    if (t < 32) sb1[t] = b1[t];

    int w = t >> 6, l = t & 63;
    int nwaves = gridDim.x * 4;
    int iters = (N + nwaves - 1) / nwaves;
    for (int it = 0; it < iters; ++it) {
        int n = blockIdx.x * 4 + w + it * nwaves;
        bool act = n < N;
        __syncthreads();
        if (act) sbuf[w][l] = ns[(size_t)n * 64 + l];
        __syncthreads();
        if (act) {
            int k = l & 31;
            float h = sb1[k];
#pragma unroll
            for (int c = 0; c < 64; ++c) h = fmaf(sbuf[w][c], sW1[c * 32 + k], h);
            float sig = 1.0f / (1.0f + __expf(-h));
            h = h * sig * (1.0f / 0.6f);
            if (l < 32) h1buf[w][l] = h;
        }
        __syncthreads();
        if (act) {
#pragma unroll
            for (int m = 0; m < 3; ++m) {
                int o = l + 64 * m;
                float a = sb2[o];
#pragma unroll
                for (int kk = 0; kk < 32; ++kk)
                    a = fmaf(h1buf[w][kk], sW2[kk * 192 + o], a);
                srow[w][o] = a;
            }
        }
        __syncthreads();
        if (act) {
            {
                int ww = l;
                if (ww < 96) {
                    int oc = ww & 31, q = ww >> 5;
                    spj_p[(size_t)n * 96 + ww] =
                        pack_bf16(srow[w][64 * q + oc], srow[w][64 * q + oc + 32]);
                }
            }
            if (l < 32) {
                int ww = 64 + l;
                int oc = ww & 31, q = ww >> 5;
                spj_p[(size_t)n * 96 + ww] =
                    pack_bf16(srow[w][64 * q + oc], srow[w][64 * q + oc + 32]);
            }
        }
    }
}

// ---------------------------------------------------------------------------
// K5: pack node_vector to bf16 pairs: word w = 32d+oc packs (192-row cols
// d*64+oc, d*64+oc+32).
// ---------------------------------------------------------------------------
__global__ void k_nvp(const float* __restrict__ nvec, unsigned* __restrict__ nvp,
                      int total /* N*96 */) {
    int idx = blockIdx.x * blockDim.x + threadIdx.x;
    if (idx >= total) return;
    int n = idx / 96, w = idx - n * 96;
    int d = w >> 5, oc = w & 31;
    size_t base = (size_t)n * 192 + d * 64 + oc;
    nvp[idx] = pack_bf16(nvec[base], nvec[base + 32]);
}

// ---------------------------------------------------------------------------
// K6: geometry features in sorted order (all coalesced now).
// ---------------------------------------------------------------------------
__global__ void k_geom_s(const float* __restrict__ ud_s, const int* __restrict__ ii_s,
                         const float* __restrict__ ref_vec,
                         const float* __restrict__ ref_sh,
                         const float* __restrict__ ln_g, const float* __restrict__ ln_b,
                         float* __restrict__ geom_s, int E) {
    int r = blockIdx.x * blockDim.x + threadIdx.x;
    if (r >= E) return;
    int i = ii_s[r];
    float ux = ud_s[3 * r], uy = ud_s[3 * r + 1], uz = ud_s[3 * r + 2];
    float esh[SH49];
    sph49(ux, uy, uz, esh);
    const float* rs = ref_sh + (size_t)i * SH49;
    float inv[7];
    int idx = 0;
#pragma unroll
    for (int l = 0; l <= 6; ++l) {
        float s = 0.f;
#pragma unroll
        for (int m = 0; m < 2 * l + 1; ++m) { s += esh[idx] * rs[idx]; idx++; }
        inv[l] = s / (float)(2 * l + 1);
    }
    float mu = 0.f;
#pragma unroll
    for (int l = 0; l < 7; ++l) mu += inv[l];
    mu *= (1.0f / 7.0f);
    float var = 0.f;
#pragma unroll
    for (int l = 0; l < 7; ++l) { float d = inv[l] - mu; var += d * d; }
    var *= (1.0f / 7.0f);
    float rstd = rsqrtf(var + 1e-5f);
    float rvx = ref_vec[3 * i], rvy = ref_vec[3 * i + 1], rvz = ref_vec[3 * i + 2];
    float ct = ux * rvx + uy * rvy + uz * rvz;
    float* g = geom_s + (size_t)r * 8;
    g[0] = ct;
#pragma unroll
    for (int l = 0; l < 7; ++l) g[1 + l] = (inv[l] - mu) * rstd * ln_g[l] + ln_b[l];
}

// ---------------------------------------------------------------------------
// K7: fused main kernel over sorted edges with per-tile LDS slot reduction.
// Epilogue is FULLY UNROLLED (static acc indices -> no scratch, rule #20)
// and W_inv/b_inv/b_edge column slices live in registers (no LDS reads).
// ---------------------------------------------------------------------------
__global__ __launch_bounds__(TPB, 2) void k_main(
    const float* __restrict__ rbf, const float* __restrict__ W_edge,
    const float* __restrict__ b_edge, const float* __restrict__ W_inv,
    const float* __restrict__ b_inv, const float* __restrict__ geom_s,
    const unsigned* __restrict__ spj_p, const unsigned* __restrict__ nvp,
    const float* __restrict__ ud_s, const int* __restrict__ ii_s,
    const int* __restrict__ jj_s, const int* __restrict__ perm,
    float* __restrict__ dscal, float* __restrict__ dvec, int E) {
    __shared__ unsigned sWp[64 * 96];    // 24.0 KB  bf16-pair packed W_edge
    __shared__ float rbfT[64 * 68];      // 17.0 KB  [k][edge]
    __shared__ float sgeom[64 * 8];      // 2.0 KB
    __shared__ float sud[64 * 3];
    __shared__ int sii[64];
    __shared__ int sjj[64];
    __shared__ int sslot[64];
    __shared__ int sfirst[64];
    __shared__ int sD;
    __shared__ float sacc[CAPS * 256];   // 24.0 KB  slot accumulators

    int t = threadIdx.x;
    int oc = t & 31;
    int er = t >> 5;  // 0..7

    for (int p = t; p < 64 * 96; p += TPB) {
        int k = p / 96, w = p - k * 96;
        int c = w & 31, q = w >> 5;
        sWp[p] = pack_bf16(W_edge[k * 192 + 64 * q + c],
                           W_edge[k * 192 + 64 * q + c + 32]);
    }

    // per-thread register copies of the tiny operands (columns oc+32m)
    float wv_inv[8][6];
#pragma unroll
    for (int c = 0; c < 8; ++c)
#pragma unroll
        for (int m = 0; m < 6; ++m)
            wv_inv[c][m] = W_inv[c * 192 + oc + 32 * m];
    float bi[6], be[6];
#pragma unroll
    for (int m = 0; m < 6; ++m) {
        bi[m] = b_inv[oc + 32 * m];
        be[m] = b_edge[oc + 32 * m];
    }

    const float inv_sqrt3 = 0.57735026918962584f;
    const float inv_sqrt_h = 0.125f;

    int ntiles = (E + TILE_E - 1) / TILE_E;
    for (int tile = blockIdx.x; tile < ntiles; tile += gridDim.x) {
        int e0 = tile * TILE_E;
        __syncthreads();   // (A) prior flush done before restage
        if (t < 64) {
            int rg = e0 + t;
            sjj[t] = (rg < E) ? jj_s[rg] : 0;
            sii[t] = (rg < E) ? ii_s[rg] : -1;
        }
        for (int p = t; p < 64 * 8; p += TPB)
            sgeom[p] = (e0 + (p >> 3) < E) ? geom_s[(size_t)e0 * 8 + p] : 0.f;
        for (int p = t; p < 64 * 3; p += TPB)
            sud[p] = (e0 + p / 3 < E) ? ud_s[(size_t)e0 * 3 + p] : 0.f;
        {
            int w = t >> 6, l = t & 63;
#pragma unroll
            for (int p = 0; p < 16; ++p) {
                int r = w + 4 * p;
                int rg = e0 + r;
                float v = 0.f;
                if (rg < E) {
                    int eg = perm[rg];
                    v = rbf[(size_t)eg * 64 + l];
                }
                rbfT[l * 68 + r] = v;
            }
        }
        __syncthreads();   // (B)

        // wave 0: node-boundary ballot scan -> slots
        if (t < 64) {
            bool flag = (t == 0) || (sii[t] != sii[t - 1]);
            unsigned long long bal = __ballot(flag);
            unsigned long long mask =
                (t == 63) ? ~0ull : ((1ull << (t + 1)) - 1ull);
            int slot = __popcll(bal & mask) - 1;
            sslot[t] = slot;
            if (flag) sfirst[slot] = t;
            if (t == 0) sD = __popcll(bal);
        }

        // ---- GEMM: acc[e][m] = sum_k rbf[e][k] * W[k][oc+32m] ----
        float acc[8][6];
#pragma unroll
        for (int e = 0; e < 8; ++e)
#pragma unroll
            for (int m = 0; m < 6; ++m) acc[e][m] = 0.f;

        const float* rb = &rbfT[er * 8];
#pragma unroll 4
        for (int k = 0; k < 64; ++k) {
            float4 r0 = *(const float4*)&rb[k * 68];
            float4 r1 = *(const float4*)&rb[k * 68 + 4];
            unsigned w0 = sWp[k * 96 + oc];
            unsigned w1 = sWp[k * 96 + oc + 32];
            unsigned w2 = sWp[k * 96 + oc + 64];
            float wv[6] = {bf16_lo(w0), bf16_hi(w0), bf16_lo(w1),
                           bf16_hi(w1), bf16_lo(w2), bf16_hi(w2)};
            float re[8] = {r0.x, r0.y, r0.z, r0.w, r1.x, r1.y, r1.z, r1.w};
#pragma unroll
            for (int e = 0; e < 8; ++e)
#pragma unroll
                for (int m = 0; m < 6; ++m)
                    acc[e][m] = fmaf(re[e], wv[m], acc[e][m]);
        }

        __syncthreads();   // (C) scan results visible; GEMM done
        int D = sD;
        bool slotmode = (D <= CAPS);
        if (slotmode) {
            for (int p = t; p < D * 256; p += TPB) sacc[p] = 0.f;
        }
        __syncthreads();   // (D) sacc zeroed before atomics

        // ---- epilogue: FULLY UNROLLED; run-accumulate; flush LDS/global ----
        float a_s0 = 0.f, a_s1 = 0.f;
        float a_v[3][2] = {{0.f, 0.f}, {0.f, 0.f}, {0.f, 0.f}};
        int runi = -1, runslot = -1;
        bool any = false;
#pragma unroll
        for (int e = 0; e < 8; ++e) {
            int el = er * 8 + e;
            int rg = e0 + el;
            if (rg < E) {
                int j = sjj[el], i = sii[el];
                if (i != runi) {
                    if (any) {
                        if (slotmode) {
                            float* sa = &sacc[runslot * 256];
                            atomicAdd(&sa[oc], a_s0);
                            atomicAdd(&sa[oc + 32], a_s1);
#pragma unroll
                            for (int d = 0; d < 3; ++d) {
                                atomicAdd(&sa[64 + d * 64 + oc], a_v[d][0]);
                                atomicAdd(&sa[64 + d * 64 + oc + 32], a_v[d][1]);
                            }
                        } else {
                            atomicAdd(&dscal[(size_t)runi * 64 + oc], a_s0);
                            atomicAdd(&dscal[(size_t)runi * 64 + oc + 32], a_s1);
#pragma unroll
                            for (int d = 0; d < 3; ++d) {
                                atomicAdd(&dvec[(size_t)runi * 192 + d * 64 + oc], a_v[d][0]);
                                atomicAdd(&dvec[(size_t)runi * 192 + d * 64 + oc + 32], a_v[d][1]);
                            }
                        }
                    }
                    a_s0 = 0.f; a_s1 = 0.f;
#pragma unroll
                    for (int d = 0; d < 3; ++d) { a_v[d][0] = 0.f; a_v[d][1] = 0.f; }
                    runi = i; runslot = sslot[el];
                }
                any = true;
                // geometry features: two float4 LDS reads
                float4 g0 = *(const float4*)&sgeom[el * 8];
                float4 g1 = *(const float4*)&sgeom[el * 8 + 4];
                float g8[8] = {g0.x, g0.y, g0.z, g0.w, g1.x, g1.y, g1.z, g1.w};
                // gathers (bf16-packed rows, 3 dwords each)
                unsigned sp0 = spj_p[(size_t)j * 96 + oc];
                unsigned sp1 = spj_p[(size_t)j * 96 + oc + 32];
                unsigned sp2 = spj_p[(size_t)j * 96 + oc + 64];
                unsigned nv0 = nvp[(size_t)j * 96 + oc];
                unsigned nv1 = nvp[(size_t)j * 96 + oc + 32];
                unsigned nv2 = nvp[(size_t)j * 96 + oc + 64];
                float sp[6] = {bf16_lo(sp0), bf16_hi(sp0), bf16_lo(sp1),
                               bf16_hi(sp1), bf16_lo(sp2), bf16_hi(sp2)};
                float x[6];
#pragma unroll
                for (int m = 0; m < 6; ++m) {
                    float u = bi[m];
#pragma unroll
                    for (int c = 0; c < 8; ++c)
                        u = fmaf(g8[c], wv_inv[c][m], u);
                    float sig = 1.0f / (1.0f + __expf(-u));
                    float v = u * sig * (1.0f / 0.6f);
                    v = fminf(fmaxf(v, -20.f), 20.f);
                    float e2v = __expf(2.0f * v);
                    float gate = (e2v - 1.0f) / (e2v + 1.0f);
                    float rh = (acc[e][m] + be[m]) * (1.0f + gate);
                    x[m] = sp[m] * rh * inv_sqrt3;
                }
                a_s0 += x[4];
                a_s1 += x[5];
                float udv[3] = {sud[el * 3], sud[el * 3 + 1], sud[el * 3 + 2]};
                unsigned nw[3] = {nv0, nv1, nv2};
#pragma unroll
                for (int d = 0; d < 3; ++d) {
                    a_v[d][0] += (x[0] * bf16_lo(nw[d]) + x[2] * udv[d]) * inv_sqrt_h;
                    a_v[d][1] += (x[1] * bf16_hi(nw[d]) + x[3] * udv[d]) * inv_sqrt_h;
                }
            }
        }
        if (any) {
            if (slotmode) {
                float* sa = &sacc[runslot * 256];
                atomicAdd(&sa[oc], a_s0);
                atomicAdd(&sa[oc + 32], a_s1);
#pragma unroll
                for (int d = 0; d < 3; ++d) {
                    atomicAdd(&sa[64 + d * 64 + oc], a_v[d][0]);
                    atomicAdd(&sa[64 + d * 64 + oc + 32], a_v[d][1]);
                }
            } else {
                atomicAdd(&dscal[(size_t)runi * 64 + oc], a_s0);
                atomicAdd(&dscal[(size_t)runi * 64 + oc + 32], a_s1);
#pragma unroll
                for (int d = 0; d < 3; ++d) {
                    atomicAdd(&dvec[(size_t)runi * 192 + d * 64 + oc], a_v[d][0]);
                    atomicAdd(&dvec[(size_t)runi * 192 + d * 64 + oc + 32], a_v[d][1]);
                }
            }
        }
        __syncthreads();   // (E) all LDS atomics done

        // ---- flush slots: interior = plain store, boundary = atomic ----
        if (slotmode) {
            int Dreal = D - ((sii[63] < 0) ? 1 : 0);
            for (int s = 0; s < D; ++s) {
                int n = sii[sfirst[s]];
                if (n < 0) continue;
                float val = sacc[s * 256 + t];
                bool boundary = (s == 0) || (s == Dreal - 1);
                float* ptr = (t < 64) ? &dscal[(size_t)n * 64 + t]
                                      : &dvec[(size_t)n * 192 + (t - 64)];
                if (boundary) atomicAdd(ptr, val);
                else *ptr = val;
            }
        }
    }
}

// ---------------------------------------------------------------------------
extern "C" void kernel_launch(void* const* d_in, const int* in_sizes, int n_in,
                              void* d_out, int out_size, void* d_ws, size_t ws_size,
                              hipStream_t stream) {
    const float* node_scalar = (const float*)d_in[0];
    const float* node_vector = (const float*)d_in[1];
    const float* edge_rbf    = (const float*)d_in[2];
    const float* edge_udiff  = (const float*)d_in[3];
    const int*   edge_index  = (const int*)d_in[4];
    const float* W_edge      = (const float*)d_in[5];
    const float* b_edge      = (const float*)d_in[6];
    const float* W_x1        = (const float*)d_in[7];
    const float* b_x1        = (const float*)d_in[8];
    const float* W_x2        = (const float*)d_in[9];
    const float* b_x2        = (const float*)d_in[10];
    const float* ln_g        = (const float*)d_in[11];
    const float* ln_b        = (const float*)d_in[12];
    const float* W_inv       = (const float*)d_in[13];
    const float* b_inv       = (const float*)d_in[14];

    int N = in_sizes[0] / 64;
    int E = in_sizes[3] / 3;

    float* ws = (float*)d_ws;
    size_t o = 0;
    int*      icnt   = (int*)(ws + o); o += N;
    int*      offs   = (int*)(ws + o); o += N;
    int*      cursor = (int*)(ws + o); o += N;
    int*      bsum   = (int*)(ws + o); o += 1024;
    float*    ref_vec= ws + o; o += (size_t)N * 3;
    float*    ref_sh = ws + o; o += (size_t)N * SH49;
    unsigned* spj_p  = (unsigned*)(ws + o); o += (size_t)N * 96;
    unsigned* nvp    = (unsigned*)(ws + o); o += (size_t)N * 96;
    int*      perm   = (int*)(ws + o); o += E;
    float*    geom_s = ws + o; o += (size_t)E * 8;
    float*    ud_s   = ws + o; o += (size_t)E * 3;
    int*      ii_s   = (int*)(ws + o); o += E;
    int*      jj_s   = (int*)(ws + o); o += E;

    float* dscal = (float*)d_out;                       // N*64
    float* dvec  = (float*)d_out + (size_t)N * 64;      // N*192

    hipMemsetAsync(icnt, 0, (size_t)N * sizeof(int), stream);
    hipMemsetAsync(d_out, 0, (size_t)out_size * sizeof(float), stream);

    int nb = (N + SCB - 1) / SCB;

    k_hist<<<(E + TPB - 1) / TPB, TPB, 0, stream>>>(edge_index, icnt, E);
    k_scan1<<<nb, SCB, 0, stream>>>(icnt, offs, bsum, N);
    k_scan2<<<1, 1024, 0, stream>>>(bsum, nb);
    k_scan3<<<nb, SCB, 0, stream>>>(offs, bsum, cursor, N);
    k_perm<<<(E + TPB - 1) / TPB, TPB, 0, stream>>>(edge_udiff, edge_index, cursor,
                                                    perm, ii_s, jj_s, ud_s, E);
    k_node_ref<<<(N + TPB - 1) / TPB, TPB, 0, stream>>>(offs, icnt, ud_s,
                                                        ref_vec, ref_sh, N);
    k_sproj<<<512, TPB, 0, stream>>>(node_scalar, W_x1, b_x1, W_x2, b_x2, spj_p, N);
    k_nvp<<<(N * 96 + TPB - 1) / TPB, TPB, 0, stream>>>(node_vector, nvp, N * 96);
    k_geom_s<<<(E + TPB - 1) / TPB, TPB, 0, stream>>>(ud_s, ii_s, ref_vec, ref_sh,
                                                      ln_g, ln_b, geom_s, E);
    k_main<<<512, TPB, 0, stream>>>(edge_rbf, W_edge, b_edge, W_inv, b_inv, geom_s,
                                    spj_p, nvp, ud_s, ii_s, jj_s, perm,
                                    dscal, dvec, E);
}

// Round 6
// 632.400 us; speedup vs baseline: 1.4267x; 1.2506x over previous
//
#include <hip/hip_runtime.h>
#include <math.h>

#define LMAXX 6
#define SH49 49
#define TPB 256
#define TILE_E 64
#define SCB 256
#define CAPS 14   // max distinct nodes per tile for LDS slot path

typedef __attribute__((ext_vector_type(8))) short short8v;
typedef __attribute__((ext_vector_type(16))) float f32x16;
union FragU { short8v v; uint2 u2[2]; };

// ---------------------------------------------------------------------------
// bf16 pack/unpack helpers (RNE)
// ---------------------------------------------------------------------------
__device__ __forceinline__ unsigned pack_bf16(float a, float b) {
    unsigned ua = __float_as_uint(a);
    unsigned ub = __float_as_uint(b);
    ua += 0x7fffu + ((ua >> 16) & 1u);
    ub += 0x7fffu + ((ub >> 16) & 1u);
    return (ua >> 16) | (ub & 0xffff0000u);
}
__device__ __forceinline__ float bf16_lo(unsigned w) { return __uint_as_float(w << 16); }
__device__ __forceinline__ float bf16_hi(unsigned w) { return __uint_as_float(w & 0xffff0000u); }

// ---------------------------------------------------------------------------
// Real spherical harmonics up to l=6, 'component' normalization.
// ---------------------------------------------------------------------------
__device__ __forceinline__ void sph49(float x, float y, float z, float* sh) {
    float nn = sqrtf(x * x + y * y + z * z + 1e-12f);
    float iv = 1.0f / nn;
    x *= iv; y *= iv; z *= iv;
    float st2 = x * x + y * y;
    float st = sqrtf(st2 > 0.f ? st2 : 0.f);
    float cphi, sphi;
    if (st > 1e-30f) { cphi = x / st; sphi = y / st; }
    else { cphi = 1.0f; sphi = 0.0f; }

    float P[LMAXX + 1][LMAXX + 1];
    P[0][0] = 0.28209479177387814f;
#pragma unroll
    for (int m = 1; m <= LMAXX; ++m)
        P[m][m] = -sqrtf((2.f * m + 1.f) / (2.f * m)) * st * P[m - 1][m - 1];
#pragma unroll
    for (int m = 0; m < LMAXX; ++m)
        P[m + 1][m] = sqrtf(2.f * m + 3.f) * z * P[m][m];
#pragma unroll
    for (int m = 0; m <= LMAXX; ++m) {
#pragma unroll
        for (int l = m + 2; l <= LMAXX; ++l) {
            float a = sqrtf((4.f * l * l - 1.f) / (float)(l * l - m * m));
            float b = sqrtf((float)((l - 1) * (l - 1) - m * m) /
                            (4.f * (l - 1) * (l - 1) - 1.f));
            P[l][m] = a * (z * P[l - 1][m] - b * P[l - 2][m]);
        }
    }
    float cm[LMAXX + 1], sm[LMAXX + 1];
    cm[0] = 1.f; sm[0] = 0.f; cm[1] = cphi; sm[1] = sphi;
#pragma unroll
    for (int m = 2; m <= LMAXX; ++m) {
        cm[m] = 2.f * cphi * cm[m - 1] - cm[m - 2];
        sm[m] = 2.f * cphi * sm[m - 1] - sm[m - 2];
    }
    const float s4pi = 3.5449077018110318f;
    const float s8pi = 5.0132565492620005f;
    int idx = 0;
#pragma unroll
    for (int l = 0; l <= LMAXX; ++l) {
#pragma unroll
        for (int mm = -l; mm <= l; ++mm) {
            if (mm < 0)       sh[idx++] = s8pi * P[l][-mm] * sm[-mm];
            else if (mm == 0) sh[idx++] = s4pi * P[l][0];
            else              sh[idx++] = s8pi * P[l][mm] * cm[mm];
        }
    }
}

// ---------------------------------------------------------------------------
// K1: destination-degree histogram (int atomics only).
// ---------------------------------------------------------------------------
__global__ void k_hist(const int* __restrict__ eidx, int* __restrict__ icnt, int E) {
    int e = blockIdx.x * blockDim.x + threadIdx.x;
    if (e >= E) return;
    atomicAdd(&icnt[eidx[E + e]], 1);
}

// ---------------------------------------------------------------------------
// Counting-sort scan kernels: exclusive prefix over icnt[N].
// ---------------------------------------------------------------------------
__global__ void k_scan1(const int* __restrict__ icnt, int* __restrict__ offs,
                        int* __restrict__ bsum, int N) {
    __shared__ int s[SCB];
    int t = threadIdx.x;
    int idx = blockIdx.x * SCB + t;
    int v = (idx < N) ? icnt[idx] : 0;
    s[t] = v; __syncthreads();
#pragma unroll
    for (int off = 1; off < SCB; off <<= 1) {
        int u = (t >= off) ? s[t - off] : 0;
        __syncthreads();
        s[t] += u;
        __syncthreads();
    }
    if (idx < N) offs[idx] = s[t] - v;
    if (t == SCB - 1) bsum[blockIdx.x] = s[t];
}

__global__ void k_scan2(int* __restrict__ bsum, int nb) {
    __shared__ int s[1024];
    int t = threadIdx.x;
    int v = (t < nb) ? bsum[t] : 0;
    s[t] = v; __syncthreads();
#pragma unroll
    for (int off = 1; off < 1024; off <<= 1) {
        int u = (t >= off) ? s[t - off] : 0;
        __syncthreads();
        s[t] += u;
        __syncthreads();
    }
    if (t < nb) bsum[t] = s[t] - v;
}

__global__ void k_scan3(int* __restrict__ offs, const int* __restrict__ bsum,
                        int* __restrict__ cursor, int N) {
    int idx = blockIdx.x * SCB + threadIdx.x;
    if (idx >= N) return;
    int o = offs[idx] + bsum[blockIdx.x];
    offs[idx] = o;
    cursor[idx] = o;
}

// ---------------------------------------------------------------------------
// K2: build permutation + scatter edge data into sorted (by dest i) order.
// ---------------------------------------------------------------------------
__global__ void k_perm(const float* __restrict__ ud, const int* __restrict__ eidx,
                       int* __restrict__ cursor, int* __restrict__ perm,
                       int* __restrict__ ii_s, int* __restrict__ jj_s,
                       float* __restrict__ ud_s, int E) {
    int e = blockIdx.x * blockDim.x + threadIdx.x;
    if (e >= E) return;
    int i = eidx[E + e];
    int j = eidx[e];
    int pos = atomicAdd(&cursor[i], 1);
    perm[pos] = e;
    ii_s[pos] = i;
    jj_s[pos] = j;
    ud_s[3 * pos + 0] = ud[3 * e + 0];
    ud_s[3 * pos + 1] = ud[3 * e + 1];
    ud_s[3 * pos + 2] = ud[3 * e + 2];
}

// ---------------------------------------------------------------------------
// K3: per-node ref_vec via CSR segment sum (no atomics) + ref SH.
// ---------------------------------------------------------------------------
__global__ void k_node_ref(const int* __restrict__ offs, const int* __restrict__ icnt,
                           const float* __restrict__ ud_s,
                           float* __restrict__ ref_vec, float* __restrict__ ref_sh,
                           int N) {
    int n = blockIdx.x * blockDim.x + threadIdx.x;
    if (n >= N) return;
    int o0 = offs[n], c = icnt[n];
    float sx = 0.f, sy = 0.f, sz = 0.f;
    for (int e = o0; e < o0 + c; ++e) {
        sx += ud_s[3 * e + 0];
        sy += ud_s[3 * e + 1];
        sz += ud_s[3 * e + 2];
    }
    float d = fmaxf((float)c, 1.0f);
    float vx = sx / d, vy = sy / d, vz = sz / d;
    float norm = sqrtf(vx * vx + vy * vy + vz * vz + 1e-9f);
    float ivn = 1.0f / norm;
    vx *= ivn; vy *= ivn; vz *= ivn;
    if (norm < 5e-5f) { vx = 1.f; vy = 0.f; vz = 0.f; }
    ref_vec[3 * n + 0] = vx;
    ref_vec[3 * n + 1] = vy;
    ref_vec[3 * n + 2] = vz;
    sph49(vx, vy, vz, ref_sh + (size_t)n * SH49);
}

// ---------------------------------------------------------------------------
// K4: scalar_proj, written bf16-PACKED: word w = oc+32q packs cols
// (64q+oc, 64q+oc+32) of the 192-wide row.
// ---------------------------------------------------------------------------
__global__ __launch_bounds__(TPB) void k_sproj(const float* __restrict__ ns,
                                               const float* __restrict__ W1,
                                               const float* __restrict__ b1,
                                               const float* __restrict__ W2,
                                               const float* __restrict__ b2,
                                               unsigned* __restrict__ spj_p, int N) {
    __shared__ float sW1[64 * 32];
    __shared__ float sW2[32 * 192];
    __shared__ float sb2[192];
    __shared__ float sb1[32];
    __shared__ float sbuf[4][64];
    __shared__ float h1buf[4][32];
    __shared__ float srow[4][192];
    int t = threadIdx.x;
    for (int p = t; p < 64 * 32; p += TPB) sW1[p] = W1[p];
    for (int p = t; p < 32 * 192; p += TPB) sW2[p] = W2[p];
    if (t < 192) sb2[t] = b2[t];
    if (t < 32) sb1[t] = b1[t];

    int w = t >> 6, l = t & 63;
    int nwaves = gridDim.x * 4;
    int iters = (N + nwaves - 1) / nwaves;
    for (int it = 0; it < iters; ++it) {
        int n = blockIdx.x * 4 + w + it * nwaves;
        bool act = n < N;
        __syncthreads();
        if (act) sbuf[w][l] = ns[(size_t)n * 64 + l];
        __syncthreads();
        if (act) {
            int k = l & 31;
            float h = sb1[k];
#pragma unroll
            for (int c = 0; c < 64; ++c) h = fmaf(sbuf[w][c], sW1[c * 32 + k], h);
            float sig = 1.0f / (1.0f + __expf(-h));
            h = h * sig * (1.0f / 0.6f);
            if (l < 32) h1buf[w][l] = h;
        }
        __syncthreads();
        if (act) {
#pragma unroll
            for (int m = 0; m < 3; ++m) {
                int o = l + 64 * m;
                float a = sb2[o];
#pragma unroll
                for (int kk = 0; kk < 32; ++kk)
                    a = fmaf(h1buf[w][kk], sW2[kk * 192 + o], a);
                srow[w][o] = a;
            }
        }
        __syncthreads();
        if (act) {
            {
                int ww = l;
                if (ww < 96) {
                    int oc = ww & 31, q = ww >> 5;
                    spj_p[(size_t)n * 96 + ww] =
                        pack_bf16(srow[w][64 * q + oc], srow[w][64 * q + oc + 32]);
                }
            }
            if (l < 32) {
                int ww = 64 + l;
                int oc = ww & 31, q = ww >> 5;
                spj_p[(size_t)n * 96 + ww] =
                    pack_bf16(srow[w][64 * q + oc], srow[w][64 * q + oc + 32]);
            }
        }
    }
}

// ---------------------------------------------------------------------------
// K5: pack node_vector to bf16 pairs: word w = 32d+oc packs (192-row cols
// d*64+oc, d*64+oc+32).
// ---------------------------------------------------------------------------
__global__ void k_nvp(const float* __restrict__ nvec, unsigned* __restrict__ nvp,
                      int total /* N*96 */) {
    int idx = blockIdx.x * blockDim.x + threadIdx.x;
    if (idx >= total) return;
    int n = idx / 96, w = idx - n * 96;
    int d = w >> 5, oc = w & 31;
    size_t base = (size_t)n * 192 + d * 64 + oc;
    nvp[idx] = pack_bf16(nvec[base], nvec[base + 32]);
}

// ---------------------------------------------------------------------------
// K6: geometry features in sorted order (all coalesced now).
// ---------------------------------------------------------------------------
__global__ void k_geom_s(const float* __restrict__ ud_s, const int* __restrict__ ii_s,
                         const float* __restrict__ ref_vec,
                         const float* __restrict__ ref_sh,
                         const float* __restrict__ ln_g, const float* __restrict__ ln_b,
                         float* __restrict__ geom_s, int E) {
    int r = blockIdx.x * blockDim.x + threadIdx.x;
    if (r >= E) return;
    int i = ii_s[r];
    float ux = ud_s[3 * r], uy = ud_s[3 * r + 1], uz = ud_s[3 * r + 2];
    float esh[SH49];
    sph49(ux, uy, uz, esh);
    const float* rs = ref_sh + (size_t)i * SH49;
    float inv[7];
    int idx = 0;
#pragma unroll
    for (int l = 0; l <= 6; ++l) {
        float s = 0.f;
#pragma unroll
        for (int m = 0; m < 2 * l + 1; ++m) { s += esh[idx] * rs[idx]; idx++; }
        inv[l] = s / (float)(2 * l + 1);
    }
    float mu = 0.f;
#pragma unroll
    for (int l = 0; l < 7; ++l) mu += inv[l];
    mu *= (1.0f / 7.0f);
    float var = 0.f;
#pragma unroll
    for (int l = 0; l < 7; ++l) { float d = inv[l] - mu; var += d * d; }
    var *= (1.0f / 7.0f);
    float rstd = rsqrtf(var + 1e-5f);
    float rvx = ref_vec[3 * i], rvy = ref_vec[3 * i + 1], rvz = ref_vec[3 * i + 2];
    float ct = ux * rvx + uy * rvy + uz * rvz;
    float* g = geom_s + (size_t)r * 8;
    g[0] = ct;
#pragma unroll
    for (int l = 0; l < 7; ++l) g[1 + l] = (inv[l] - mu) * rstd * ln_g[l] + ln_b[l];
}

// ---------------------------------------------------------------------------
// K7: fused main kernel, MFMA edition.
// GEMM per 64-edge tile: C[64][192] = rbf_bf16[64][64] @ W_bf16[64][192]
// via v_mfma_f32_32x32x16_bf16. Waves: (eh = edge half) x (wc = col pair).
// Wave (eh,wc) computes C-tiles at cols {32wc, 64+32wc, 128+32wc} for edges
// [32eh, 32eh+32). Lane holds cols (h, 64+h, 128+h), h = 32wc + (l&31) --
// exactly the (x1,x2,x3) triple the epilogue needs.
// A/B staged in LDS as bf16 pairs with the SAME per-slot k-order (k-perm
// invariance => correct regardless of the HW's internal k map).
// C/D layout (HW-verified): col=lane&31, row=(reg&3)+8*(reg>>2)+4*(lane>>5).
// ---------------------------------------------------------------------------
__global__ __launch_bounds__(TPB, 3) void k_main(
    const float* __restrict__ rbf, const float* __restrict__ W_edge,
    const float* __restrict__ b_edge, const float* __restrict__ W_inv,
    const float* __restrict__ b_inv, const float* __restrict__ geom_s,
    const unsigned* __restrict__ spj_p, const unsigned* __restrict__ nvp,
    const float* __restrict__ ud_s, const int* __restrict__ ii_s,
    const int* __restrict__ jj_s, const int* __restrict__ perm,
    float* __restrict__ dscal, float* __restrict__ dvec, int E) {
    __shared__ __align__(16) unsigned sWT[192 * 34];  // 25.5 KB W^T bf16 pairs [col][k/2]
    __shared__ __align__(16) unsigned rbfT[64 * 34];  // 8.5 KB  A bf16 pairs [edge][k/2]
    __shared__ __align__(16) float sgeom[64 * 8];     // 2 KB
    __shared__ float sud[64 * 3];
    __shared__ int sii[64];
    __shared__ int sjj[64];
    __shared__ int sslot[64];
    __shared__ int sfirst[64];
    __shared__ int sD;
    __shared__ float sacc[CAPS * 256];                // 14 KB slot accumulators

    int t = threadIdx.x;
    int l = t & 63;
    int wid = t >> 6;
    int eh = wid >> 1;        // edge half 0/1
    int wc = wid & 1;         // col pair 0/1
    int lo5 = l & 31;
    int hi = l >> 5;
    int h = wc * 32 + lo5;    // this lane's column triple: h, 64+h, 128+h

    // stage W^T (bf16 pairs along k) once per block
    for (int p = t; p < 192 * 32; p += TPB) {
        int col = p >> 5, kd = p & 31;
        sWT[col * 34 + kd] = pack_bf16(W_edge[(2 * kd) * 192 + col],
                                       W_edge[(2 * kd + 1) * 192 + col]);
    }

    // per-lane register copies of tiny operands for cols {h, 64+h, 128+h}
    float wv_inv[8][3];
#pragma unroll
    for (int c = 0; c < 8; ++c)
#pragma unroll
        for (int q = 0; q < 3; ++q)
            wv_inv[c][q] = W_inv[c * 192 + q * 64 + h];
    float bi[3], be[3];
#pragma unroll
    for (int q = 0; q < 3; ++q) {
        bi[q] = b_inv[q * 64 + h];
        be[q] = b_edge[q * 64 + h];
    }

    const float inv_sqrt3 = 0.57735026918962584f;
    const float inv_sqrt_h = 0.125f;

    int ntiles = (E + TILE_E - 1) / TILE_E;
    for (int tile = blockIdx.x; tile < ntiles; tile += gridDim.x) {
        int e0 = tile * TILE_E;
        __syncthreads();   // (A) prior flush done before restage
        if (t < 64) {
            int rg = e0 + t;
            sjj[t] = (rg < E) ? jj_s[rg] : 0;
            sii[t] = (rg < E) ? ii_s[rg] : -1;
        }
        for (int p = t; p < 64 * 8; p += TPB)
            sgeom[p] = (e0 + (p >> 3) < E) ? geom_s[(size_t)e0 * 8 + p] : 0.f;
        for (int p = t; p < 64 * 3; p += TPB)
            sud[p] = (e0 + p / 3 < E) ? ud_s[(size_t)e0 * 3 + p] : 0.f;
        {
            // A staging: 4 threads per edge row, each packs 16 floats -> 8 dwords
            int e = t >> 2, q4 = t & 3;
            int rg = e0 + e;
            int dst = e * 34 + q4 * 8;
            if (rg < E) {
                const float4* src = (const float4*)&rbf[(size_t)perm[rg] * 64 + q4 * 16];
                float4 v0 = src[0], v1 = src[1], v2 = src[2], v3 = src[3];
                rbfT[dst + 0] = pack_bf16(v0.x, v0.y);
                rbfT[dst + 1] = pack_bf16(v0.z, v0.w);
                rbfT[dst + 2] = pack_bf16(v1.x, v1.y);
                rbfT[dst + 3] = pack_bf16(v1.z, v1.w);
                rbfT[dst + 4] = pack_bf16(v2.x, v2.y);
                rbfT[dst + 5] = pack_bf16(v2.z, v2.w);
                rbfT[dst + 6] = pack_bf16(v3.x, v3.y);
                rbfT[dst + 7] = pack_bf16(v3.z, v3.w);
            } else {
#pragma unroll
                for (int q = 0; q < 8; ++q) rbfT[dst + q] = 0u;
            }
        }
        __syncthreads();   // (B)

        // wave 0: node-boundary ballot scan -> slots
        if (t < 64) {
            bool flag = (t == 0) || (sii[t] != sii[t - 1]);
            unsigned long long bal = __ballot(flag);
            unsigned long long mask =
                (t == 63) ? ~0ull : ((1ull << (t + 1)) - 1ull);
            int slot = __popcll(bal & mask) - 1;
            sslot[t] = slot;
            if (flag) sfirst[slot] = t;
            if (t == 0) sD = __popcll(bal);
        }

        // ---- MFMA GEMM: 3 C-tiles (32 edges x 32 cols), K = 64 (4 steps) ----
        FragU afr[4];
        int arow = lo5 + 32 * eh;
#pragma unroll
        for (int ks = 0; ks < 4; ++ks) {
            int off = arow * 34 + ks * 8 + hi * 4;
            afr[ks].u2[0] = *(const uint2*)&rbfT[off];
            afr[ks].u2[1] = *(const uint2*)&rbfT[off + 2];
        }
        f32x16 acc0 = {0.f,0.f,0.f,0.f,0.f,0.f,0.f,0.f,0.f,0.f,0.f,0.f,0.f,0.f,0.f,0.f};
        f32x16 acc1 = acc0, acc2 = acc0;
        int bc0 = (wc * 32 + lo5) * 34;
#pragma unroll
        for (int ks = 0; ks < 4; ++ks) {
            int off = ks * 8 + hi * 4;
            FragU b0, b1, b2;
            b0.u2[0] = *(const uint2*)&sWT[bc0 + off];
            b0.u2[1] = *(const uint2*)&sWT[bc0 + off + 2];
            b1.u2[0] = *(const uint2*)&sWT[bc0 + 64 * 34 + off];
            b1.u2[1] = *(const uint2*)&sWT[bc0 + 64 * 34 + off + 2];
            b2.u2[0] = *(const uint2*)&sWT[bc0 + 128 * 34 + off];
            b2.u2[1] = *(const uint2*)&sWT[bc0 + 128 * 34 + off + 2];
            acc0 = __builtin_amdgcn_mfma_f32_32x32x16_bf16(afr[ks].v, b0.v, acc0, 0, 0, 0);
            acc1 = __builtin_amdgcn_mfma_f32_32x32x16_bf16(afr[ks].v, b1.v, acc1, 0, 0, 0);
            acc2 = __builtin_amdgcn_mfma_f32_32x32x16_bf16(afr[ks].v, b2.v, acc2, 0, 0, 0);
        }

        __syncthreads();   // (C) scan + GEMM done
        int D = sD;
        bool slotmode = (D <= CAPS);
        if (slotmode) {
            for (int p = t; p < D * 256; p += TPB) sacc[p] = 0.f;
        }
        __syncthreads();   // (D) sacc zeroed before atomics

        // ---- epilogue: 16 rows/lane, run-accumulate, 4 atomics per run ----
        float a_s = 0.f, a_v0 = 0.f, a_v1 = 0.f, a_v2 = 0.f;
        int runi = -1, runslot = -1;
        auto flush = [&]() {
            if (runi < 0) return;
            if (slotmode) {
                float* sa = &sacc[runslot * 256];
                atomicAdd(&sa[h], a_s);
                atomicAdd(&sa[64 + h], a_v0);
                atomicAdd(&sa[128 + h], a_v1);
                atomicAdd(&sa[192 + h], a_v2);
            } else {
                atomicAdd(&dscal[(size_t)runi * 64 + h], a_s);
                atomicAdd(&dvec[(size_t)runi * 192 + h], a_v0);
                atomicAdd(&dvec[(size_t)runi * 192 + 64 + h], a_v1);
                atomicAdd(&dvec[(size_t)runi * 192 + 128 + h], a_v2);
            }
        };
#pragma unroll
        for (int r = 0; r < 16; ++r) {
            int el = eh * 32 + (r & 3) + 8 * (r >> 2) + 4 * hi;
            int rg = e0 + el;
            if (rg < E) {
                int i = sii[el], j = sjj[el];
                if (i != runi) {
                    flush();
                    a_s = 0.f; a_v0 = 0.f; a_v1 = 0.f; a_v2 = 0.f;
                    runi = i; runslot = sslot[el];
                }
                float4 g0 = *(const float4*)&sgeom[el * 8];
                float4 g1 = *(const float4*)&sgeom[el * 8 + 4];
                float u0 = bi[0], u1 = bi[1], u2 = bi[2];
                float gg[8] = {g0.x, g0.y, g0.z, g0.w, g1.x, g1.y, g1.z, g1.w};
#pragma unroll
                for (int c = 0; c < 8; ++c) {
                    u0 = fmaf(gg[c], wv_inv[c][0], u0);
                    u1 = fmaf(gg[c], wv_inv[c][1], u1);
                    u2 = fmaf(gg[c], wv_inv[c][2], u2);
                }
                float gate[3];
                float uu[3] = {u0, u1, u2};
#pragma unroll
                for (int q = 0; q < 3; ++q) {
                    float u = uu[q];
                    float sig = 1.0f / (1.0f + __expf(-u));
                    float v = u * sig * (1.0f / 0.6f);
                    v = fminf(fmaxf(v, -20.f), 20.f);
                    float e2v = __expf(2.0f * v);
                    gate[q] = (e2v - 1.0f) / (e2v + 1.0f);
                }
                size_t jb = (size_t)j * 96;
                unsigned spw0 = spj_p[jb + lo5];
                unsigned spw1 = spj_p[jb + 32 + lo5];
                unsigned spw2 = spj_p[jb + 64 + lo5];
                float sp0 = wc ? bf16_hi(spw0) : bf16_lo(spw0);
                float sp1 = wc ? bf16_hi(spw1) : bf16_lo(spw1);
                float sp2 = wc ? bf16_hi(spw2) : bf16_lo(spw2);
                float x1 = sp0 * (acc0[r] + be[0]) * (1.0f + gate[0]) * inv_sqrt3;
                float x2 = sp1 * (acc1[r] + be[1]) * (1.0f + gate[1]) * inv_sqrt3;
                float x3 = sp2 * (acc2[r] + be[2]) * (1.0f + gate[2]) * inv_sqrt3;
                a_s += x3;
                float ud0 = sud[el * 3], ud1 = sud[el * 3 + 1], ud2 = sud[el * 3 + 2];
                unsigned nw0 = nvp[jb + lo5];
                unsigned nw1 = nvp[jb + 32 + lo5];
                unsigned nw2 = nvp[jb + 64 + lo5];
                float nv0 = wc ? bf16_hi(nw0) : bf16_lo(nw0);
                float nv1 = wc ? bf16_hi(nw1) : bf16_lo(nw1);
                float nv2 = wc ? bf16_hi(nw2) : bf16_lo(nw2);
                a_v0 += (x1 * nv0 + x2 * ud0) * inv_sqrt_h;
                a_v1 += (x1 * nv1 + x2 * ud1) * inv_sqrt_h;
                a_v2 += (x1 * nv2 + x2 * ud2) * inv_sqrt_h;
            }
        }
        flush();
        __syncthreads();   // (E) all LDS atomics done

        // ---- flush slots: interior = plain store, boundary = atomic ----
        if (slotmode) {
            int Dreal = D - ((sii[63] < 0) ? 1 : 0);
            for (int s = 0; s < D; ++s) {
                int n = sii[sfirst[s]];
                if (n < 0) continue;
                float val = sacc[s * 256 + t];
                bool boundary = (s == 0) || (s == Dreal - 1);
                float* ptr = (t < 64) ? &dscal[(size_t)n * 64 + t]
                                      : &dvec[(size_t)n * 192 + (t - 64)];
                if (boundary) atomicAdd(ptr, val);
                else *ptr = val;
            }
        }
    }
}

// ---------------------------------------------------------------------------
extern "C" void kernel_launch(void* const* d_in, const int* in_sizes, int n_in,
                              void* d_out, int out_size, void* d_ws, size_t ws_size,
                              hipStream_t stream) {
    const float* node_scalar = (const float*)d_in[0];
    const float* node_vector = (const float*)d_in[1];
    const float* edge_rbf    = (const float*)d_in[2];
    const float* edge_udiff  = (const float*)d_in[3];
    const int*   edge_index  = (const int*)d_in[4];
    const float* W_edge      = (const float*)d_in[5];
    const float* b_edge      = (const float*)d_in[6];
    const float* W_x1        = (const float*)d_in[7];
    const float* b_x1        = (const float*)d_in[8];
    const float* W_x2        = (const float*)d_in[9];
    const float* b_x2        = (const float*)d_in[10];
    const float* ln_g        = (const float*)d_in[11];
    const float* ln_b        = (const float*)d_in[12];
    const float* W_inv       = (const float*)d_in[13];
    const float* b_inv       = (const float*)d_in[14];

    int N = in_sizes[0] / 64;
    int E = in_sizes[3] / 3;

    float* ws = (float*)d_ws;
    size_t o = 0;
    int*      icnt   = (int*)(ws + o); o += N;
    int*      offs   = (int*)(ws + o); o += N;
    int*      cursor = (int*)(ws + o); o += N;
    int*      bsum   = (int*)(ws + o); o += 1024;
    float*    ref_vec= ws + o; o += (size_t)N * 3;
    float*    ref_sh = ws + o; o += (size_t)N * SH49;
    unsigned* spj_p  = (unsigned*)(ws + o); o += (size_t)N * 96;
    unsigned* nvp    = (unsigned*)(ws + o); o += (size_t)N * 96;
    int*      perm   = (int*)(ws + o); o += E;
    float*    geom_s = ws + o; o += (size_t)E * 8;
    float*    ud_s   = ws + o; o += (size_t)E * 3;
    int*      ii_s   = (int*)(ws + o); o += E;
    int*      jj_s   = (int*)(ws + o); o += E;

    float* dscal = (float*)d_out;                       // N*64
    float* dvec  = (float*)d_out + (size_t)N * 64;      // N*192

    hipMemsetAsync(icnt, 0, (size_t)N * sizeof(int), stream);
    hipMemsetAsync(d_out, 0, (size_t)out_size * sizeof(float), stream);

    int nb = (N + SCB - 1) / SCB;

    k_hist<<<(E + TPB - 1) / TPB, TPB, 0, stream>>>(edge_index, icnt, E);
    k_scan1<<<nb, SCB, 0, stream>>>(icnt, offs, bsum, N);
    k_scan2<<<1, 1024, 0, stream>>>(bsum, nb);
    k_scan3<<<nb, SCB, 0, stream>>>(offs, bsum, cursor, N);
    k_perm<<<(E + TPB - 1) / TPB, TPB, 0, stream>>>(edge_udiff, edge_index, cursor,
                                                    perm, ii_s, jj_s, ud_s, E);
    k_node_ref<<<(N + TPB - 1) / TPB, TPB, 0, stream>>>(offs, icnt, ud_s,
                                                        ref_vec, ref_sh, N);
    k_sproj<<<512, TPB, 0, stream>>>(node_scalar, W_x1, b_x1, W_x2, b_x2, spj_p, N);
    k_nvp<<<(N * 96 + TPB - 1) / TPB, TPB, 0, stream>>>(node_vector, nvp, N * 96);
    k_geom_s<<<(E + TPB - 1) / TPB, TPB, 0, stream>>>(ud_s, ii_s, ref_vec, ref_sh,
                                                      ln_g, ln_b, geom_s, E);
    k_main<<<768, TPB, 0, stream>>>(edge_rbf, W_edge, b_edge, W_inv, b_inv, geom_s,
                                    spj_p, nvp, ud_s, ii_s, jj_s, perm,
                                    dscal, dvec, E);
}

// Round 9
// 576.213 us; speedup vs baseline: 1.5659x; 1.0975x over previous
//
#include <hip/hip_runtime.h>
#include <math.h>

#define LMAXX 6
#define TPB 256
#define TILE_E 64
#define SCB 256
#define CAPS 12   // max distinct nodes per tile for LDS slot path

typedef __attribute__((ext_vector_type(8))) short short8v;
typedef __attribute__((ext_vector_type(16))) float f32x16;
union FragU { short8v v; uint2 u2[2]; };

// ---------------------------------------------------------------------------
// bf16 pack/unpack helpers (RNE)
// ---------------------------------------------------------------------------
__device__ __forceinline__ unsigned pack_bf16(float a, float b) {
    unsigned ua = __float_as_uint(a);
    unsigned ub = __float_as_uint(b);
    ua += 0x7fffu + ((ua >> 16) & 1u);
    ub += 0x7fffu + ((ub >> 16) & 1u);
    return (ua >> 16) | (ub & 0xffff0000u);
}
__device__ __forceinline__ float bf16_lo(unsigned w) { return __uint_as_float(w << 16); }
__device__ __forceinline__ float bf16_hi(unsigned w) { return __uint_as_float(w & 0xffff0000u); }

// ---------------------------------------------------------------------------
// Direction -> (z, sin_theta, cos_phi, sin_phi), matching reference sph_harm.
// ---------------------------------------------------------------------------
__device__ __forceinline__ void dirang(float x, float y, float z,
                                       float& zo, float& st, float& cphi, float& sphi) {
    float nn = sqrtf(x * x + y * y + z * z + 1e-12f);
    float iv = 1.0f / nn;
    x *= iv; y *= iv; zo = z * iv;
    float st2 = x * x + y * y;
    st = sqrtf(st2 > 0.f ? st2 : 0.f);
    if (st > 1e-30f) { cphi = x / st; sphi = y / st; }
    else { cphi = 1.0f; sphi = 0.0f; }
}

// Associated Legendre table (component normalization, as in reference).
__device__ __forceinline__ void legP(float z, float st, float P[7][7]) {
    P[0][0] = 0.28209479177387814f;
#pragma unroll
    for (int m = 1; m <= LMAXX; ++m)
        P[m][m] = -sqrtf((2.f * m + 1.f) / (2.f * m)) * st * P[m - 1][m - 1];
#pragma unroll
    for (int m = 0; m < LMAXX; ++m)
        P[m + 1][m] = sqrtf(2.f * m + 3.f) * z * P[m][m];
#pragma unroll
    for (int m = 0; m <= LMAXX; ++m) {
#pragma unroll
        for (int l = m + 2; l <= LMAXX; ++l) {
            float a = sqrtf((4.f * l * l - 1.f) / (float)(l * l - m * m));
            float b = sqrtf((float)((l - 1) * (l - 1) - m * m) /
                            (4.f * (l - 1) * (l - 1) - 1.f));
            P[l][m] = a * (z * P[l - 1][m] - b * P[l - 2][m]);
        }
    }
}

// ---------------------------------------------------------------------------
// K1: destination-degree histogram (int atomics only).
// ---------------------------------------------------------------------------
__global__ void k_hist(const int* __restrict__ eidx, int* __restrict__ icnt, int E) {
    int e = blockIdx.x * blockDim.x + threadIdx.x;
    if (e >= E) return;
    atomicAdd(&icnt[eidx[E + e]], 1);
}

// ---------------------------------------------------------------------------
// Counting-sort scan kernels: exclusive prefix over icnt[N].
// ---------------------------------------------------------------------------
__global__ void k_scan1(const int* __restrict__ icnt, int* __restrict__ offs,
                        int* __restrict__ bsum, int N) {
    __shared__ int s[SCB];
    int t = threadIdx.x;
    int idx = blockIdx.x * SCB + t;
    int v = (idx < N) ? icnt[idx] : 0;
    s[t] = v; __syncthreads();
#pragma unroll
    for (int off = 1; off < SCB; off <<= 1) {
        int u = (t >= off) ? s[t - off] : 0;
        __syncthreads();
        s[t] += u;
        __syncthreads();
    }
    if (idx < N) offs[idx] = s[t] - v;
    if (t == SCB - 1) bsum[blockIdx.x] = s[t];
}

__global__ void k_scan2(int* __restrict__ bsum, int nb) {
    __shared__ int s[1024];
    int t = threadIdx.x;
    int v = (t < nb) ? bsum[t] : 0;
    s[t] = v; __syncthreads();
#pragma unroll
    for (int off = 1; off < 1024; off <<= 1) {
        int u = (t >= off) ? s[t - off] : 0;
        __syncthreads();
        s[t] += u;
        __syncthreads();
    }
    if (t < nb) bsum[t] = s[t] - v;
}

__global__ void k_scan3(int* __restrict__ offs, const int* __restrict__ bsum,
                        int* __restrict__ cursor, int N) {
    int idx = blockIdx.x * SCB + threadIdx.x;
    if (idx >= N) return;
    int o = offs[idx] + bsum[blockIdx.x];
    offs[idx] = o;
    cursor[idx] = o;
}

// ---------------------------------------------------------------------------
// K2: build permutation + scatter edge data into sorted (by dest i) order.
// ---------------------------------------------------------------------------
__global__ void k_perm(const float* __restrict__ ud, const int* __restrict__ eidx,
                       int* __restrict__ cursor, int* __restrict__ perm,
                       int* __restrict__ ii_s, int* __restrict__ jj_s,
                       float* __restrict__ ud_s, int E) {
    int e = blockIdx.x * blockDim.x + threadIdx.x;
    if (e >= E) return;
    int i = eidx[E + e];
    int j = eidx[e];
    int pos = atomicAdd(&cursor[i], 1);
    perm[pos] = e;
    ii_s[pos] = i;
    jj_s[pos] = j;
    ud_s[3 * pos + 0] = ud[3 * e + 0];
    ud_s[3 * pos + 1] = ud[3 * e + 1];
    ud_s[3 * pos + 2] = ud[3 * e + 2];
}

// ---------------------------------------------------------------------------
// K3: per-node ref_vec via CSR segment sum (no atomics). No SH here anymore.
// ---------------------------------------------------------------------------
__global__ void k_node_ref(const int* __restrict__ offs, const int* __restrict__ icnt,
                           const float* __restrict__ ud_s,
                           float* __restrict__ ref_vec, int N) {
    int n = blockIdx.x * blockDim.x + threadIdx.x;
    if (n >= N) return;
    int o0 = offs[n], c = icnt[n];
    float sx = 0.f, sy = 0.f, sz = 0.f;
    for (int e = o0; e < o0 + c; ++e) {
        sx += ud_s[3 * e + 0];
        sy += ud_s[3 * e + 1];
        sz += ud_s[3 * e + 2];
    }
    float d = fmaxf((float)c, 1.0f);
    float vx = sx / d, vy = sy / d, vz = sz / d;
    float norm = sqrtf(vx * vx + vy * vy + vz * vz + 1e-9f);
    float ivn = 1.0f / norm;
    vx *= ivn; vy *= ivn; vz *= ivn;
    if (norm < 5e-5f) { vx = 1.f; vy = 0.f; vz = 0.f; }
    ref_vec[3 * n + 0] = vx;
    ref_vec[3 * n + 1] = vy;
    ref_vec[3 * n + 2] = vz;
}

// ---------------------------------------------------------------------------
// K4: fused scalar_proj + node_vector pack -> combined gather array.
// gat[n][plane][h], h=0..63:
//   plane0[h] = (sp_h,     sp_{64+h})
//   plane1[h] = (sp_{128+h}, nv_h)
//   plane2[h] = (nv_{64+h}, nv_{128+h})
// Lane h of k_main reads 3 dwords -> all 6 bf16 it needs.
// ---------------------------------------------------------------------------
__global__ __launch_bounds__(TPB) void k_sprojv(const float* __restrict__ ns,
                                                const float* __restrict__ W1,
                                                const float* __restrict__ b1,
                                                const float* __restrict__ W2,
                                                const float* __restrict__ b2,
                                                const float* __restrict__ nvec,
                                                unsigned* __restrict__ gat, int N) {
    __shared__ float sW1[64 * 32];
    __shared__ float sW2[32 * 192];
    __shared__ float sb2[192];
    __shared__ float sb1[32];
    __shared__ float sbuf[4][64];
    __shared__ float h1buf[4][32];
    int t = threadIdx.x;
    for (int p = t; p < 64 * 32; p += TPB) sW1[p] = W1[p];
    for (int p = t; p < 32 * 192; p += TPB) sW2[p] = W2[p];
    if (t < 192) sb2[t] = b2[t];
    if (t < 32) sb1[t] = b1[t];

    int w = t >> 6, l = t & 63;
    int nwaves = gridDim.x * 4;
    int iters = (N + nwaves - 1) / nwaves;
    for (int it = 0; it < iters; ++it) {
        int n = blockIdx.x * 4 + w + it * nwaves;
        bool act = n < N;
        __syncthreads();
        if (act) sbuf[w][l] = ns[(size_t)n * 64 + l];
        __syncthreads();
        if (act) {
            int k = l & 31;
            float h = sb1[k];
#pragma unroll
            for (int c = 0; c < 64; ++c) h = fmaf(sbuf[w][c], sW1[c * 32 + k], h);
            float sig = 1.0f / (1.0f + __expf(-h));
            h = h * sig * (1.0f / 0.6f);
            if (l < 32) h1buf[w][l] = h;
        }
        __syncthreads();
        if (act) {
            // lane l owns cols l, 64+l, 128+l
            float a[3];
#pragma unroll
            for (int m = 0; m < 3; ++m) {
                int o = l + 64 * m;
                float acc = sb2[o];
#pragma unroll
                for (int kk = 0; kk < 32; ++kk)
                    acc = fmaf(h1buf[w][kk], sW2[kk * 192 + o], acc);
                a[m] = acc;
            }
            size_t nb = (size_t)n * 192;
            float nv0 = nvec[nb + l];
            float nv1 = nvec[nb + 64 + l];
            float nv2 = nvec[nb + 128 + l];
            gat[nb + l]        = pack_bf16(a[0], a[1]);
            gat[nb + 64 + l]   = pack_bf16(a[2], nv0);
            gat[nb + 128 + l]  = pack_bf16(nv1, nv2);
        }
    }
}

// ---------------------------------------------------------------------------
// K5: geometry features in sorted order. Ref-SH computed INLINE from
// ref_vec[i] (3-dword broadcast gather) via lockstep Legendre product:
//   inv[l] = (4pi/(2l+1)) * [ Pe_l0*Pr_l0 + sum_m 2*Pe_lm*Pr_lm*cos(m(phiE-phiR)) ]
// ---------------------------------------------------------------------------
__global__ void k_geom_s(const float* __restrict__ ud_s, const int* __restrict__ ii_s,
                         const float* __restrict__ ref_vec,
                         const float* __restrict__ ln_g, const float* __restrict__ ln_b,
                         float* __restrict__ geom_s, int E) {
    int r = blockIdx.x * blockDim.x + threadIdx.x;
    if (r >= E) return;
    int i = ii_s[r];
    float ux = ud_s[3 * r], uy = ud_s[3 * r + 1], uz = ud_s[3 * r + 2];
    float rvx = ref_vec[3 * i], rvy = ref_vec[3 * i + 1], rvz = ref_vec[3 * i + 2];

    float zE, stE, cpE, spE, zR, stR, cpR, spR;
    dirang(ux, uy, uz, zE, stE, cpE, spE);
    dirang(rvx, rvy, rvz, zR, stR, cpR, spR);

    float Pe[7][7], Pr[7][7];
    legP(zE, stE, Pe);
    legP(zR, stR, Pr);

    float cmE[7], smE[7], cmR[7], smR[7];
    cmE[0] = 1.f; smE[0] = 0.f; cmE[1] = cpE; smE[1] = spE;
    cmR[0] = 1.f; smR[0] = 0.f; cmR[1] = cpR; smR[1] = spR;
#pragma unroll
    for (int m = 2; m <= LMAXX; ++m) {
        cmE[m] = 2.f * cpE * cmE[m - 1] - cmE[m - 2];
        smE[m] = 2.f * cpE * smE[m - 1] - smE[m - 2];
        cmR[m] = 2.f * cpR * cmR[m - 1] - cmR[m - 2];
        smR[m] = 2.f * cpR * smR[m - 1] - smR[m - 2];
    }

    float inv[7];
#pragma unroll
    for (int l = 0; l <= LMAXX; ++l) inv[l] = Pe[l][0] * Pr[l][0];
#pragma unroll
    for (int m = 1; m <= LMAXX; ++m) {
        float cross = cmE[m] * cmR[m] + smE[m] * smR[m];
#pragma unroll
        for (int l = m; l <= LMAXX; ++l)
            inv[l] += 2.f * Pe[l][m] * Pr[l][m] * cross;
    }
    const float fourpi = 12.566370614359172f;
#pragma unroll
    for (int l = 0; l <= LMAXX; ++l) inv[l] *= fourpi / (float)(2 * l + 1);

    float mu = 0.f;
#pragma unroll
    for (int l = 0; l < 7; ++l) mu += inv[l];
    mu *= (1.0f / 7.0f);
    float var = 0.f;
#pragma unroll
    for (int l = 0; l < 7; ++l) { float d = inv[l] - mu; var += d * d; }
    var *= (1.0f / 7.0f);
    float rstd = rsqrtf(var + 1e-5f);
    float ct = ux * rvx + uy * rvy + uz * rvz;
    float* g = geom_s + (size_t)r * 8;
    g[0] = ct;
#pragma unroll
    for (int l = 0; l < 7; ++l) g[1 + l] = (inv[l] - mu) * rstd * ln_g[l] + ln_b[l];
}

// ---------------------------------------------------------------------------
// K6: fused main kernel, MFMA + slimmed LDS (4 blocks/CU).
// A-fragments perm-gathered direct from global (no rbfT LDS);
// epilogue broadcast-reads geom/ud/jj direct; combined 3-dword gat gather.
// ---------------------------------------------------------------------------
__global__ __launch_bounds__(TPB, 4) void k_main(
    const float* __restrict__ rbf, const float* __restrict__ W_edge,
    const float* __restrict__ b_edge, const float* __restrict__ W_inv,
    const float* __restrict__ b_inv, const float* __restrict__ geom_s,
    const unsigned* __restrict__ gat, const float* __restrict__ ud_s,
    const int* __restrict__ ii_s, const int* __restrict__ jj_s,
    const int* __restrict__ perm,
    float* __restrict__ dscal, float* __restrict__ dvec, int E) {
    __shared__ __align__(16) unsigned sWT[192 * 34];  // 25.5 KB W^T bf16 pairs [col][k/2]
    __shared__ int sii[64];
    __shared__ int sslot[64];
    __shared__ int sfirst[64];
    __shared__ int sD;
    __shared__ float sacc[CAPS * 256];                // 12 KB slot accumulators

    int t = threadIdx.x;
    int l = t & 63;
    int wid = t >> 6;
    int eh = wid >> 1;        // edge half 0/1
    int wc = wid & 1;         // col pair 0/1
    int lo5 = l & 31;
    int hi = l >> 5;
    int h = wc * 32 + lo5;    // this lane's column triple: h, 64+h, 128+h

    // stage W^T (bf16 pairs along k) once per block
    for (int p = t; p < 192 * 32; p += TPB) {
        int col = p >> 5, kd = p & 31;
        sWT[col * 34 + kd] = pack_bf16(W_edge[(2 * kd) * 192 + col],
                                       W_edge[(2 * kd + 1) * 192 + col]);
    }

    // per-lane register copies of tiny operands for cols {h, 64+h, 128+h}
    float wv_inv[8][3];
#pragma unroll
    for (int c = 0; c < 8; ++c)
#pragma unroll
        for (int q = 0; q < 3; ++q)
            wv_inv[c][q] = W_inv[c * 192 + q * 64 + h];
    float bi[3], be[3];
#pragma unroll
    for (int q = 0; q < 3; ++q) {
        bi[q] = b_inv[q * 64 + h];
        be[q] = b_edge[q * 64 + h];
    }

    const float inv_sqrt3 = 0.57735026918962584f;
    const float inv_sqrt_h = 0.125f;

    int ntiles = (E + TILE_E - 1) / TILE_E;
    for (int tile = blockIdx.x; tile < ntiles; tile += gridDim.x) {
        int e0 = tile * TILE_E;
        __syncthreads();   // (A) prior flush done; sWT staged (first iter)
        if (t < 64) {
            int rg = e0 + t;
            sii[t] = (rg < E) ? ii_s[rg] : -1;
        }
        __syncthreads();   // (B)

        // wave 0: node-boundary ballot scan -> slots
        if (t < 64) {
            bool flag = (t == 0) || (sii[t] != sii[t - 1]);
            unsigned long long bal = __ballot(flag);
            unsigned long long mask =
                (t == 63) ? ~0ull : ((1ull << (t + 1)) - 1ull);
            int slot = __popcll(bal & mask) - 1;
            sslot[t] = slot;
            if (flag) sfirst[slot] = t;
            if (t == 0) sD = __popcll(bal);
        }

        // ---- A-fragments: perm-gather direct from global, pack to bf16 ----
        FragU afr[4];
        int arow = lo5 + 32 * eh;
        int rga = e0 + arow;
        if (rga < E) {
            int row = perm[rga];
            const float4* rp = (const float4*)&rbf[(size_t)row * 64 + hi * 8];
#pragma unroll
            for (int ks = 0; ks < 4; ++ks) {
                float4 f0 = rp[ks * 4];
                float4 f1 = rp[ks * 4 + 1];
                afr[ks].u2[0] = make_uint2(pack_bf16(f0.x, f0.y), pack_bf16(f0.z, f0.w));
                afr[ks].u2[1] = make_uint2(pack_bf16(f1.x, f1.y), pack_bf16(f1.z, f1.w));
            }
        } else {
#pragma unroll
            for (int ks = 0; ks < 4; ++ks) {
                afr[ks].u2[0] = make_uint2(0u, 0u);
                afr[ks].u2[1] = make_uint2(0u, 0u);
            }
        }

        // ---- MFMA GEMM: 3 C-tiles (32 edges x 32 cols), K = 64 (4 steps) ----
        f32x16 acc0 = {0.f,0.f,0.f,0.f,0.f,0.f,0.f,0.f,0.f,0.f,0.f,0.f,0.f,0.f,0.f,0.f};
        f32x16 acc1 = acc0, acc2 = acc0;
        int bc0 = (wc * 32 + lo5) * 34;
#pragma unroll
        for (int ks = 0; ks < 4; ++ks) {
            int off = ks * 8 + hi * 4;
            FragU b0, b1, b2;
            b0.u2[0] = *(const uint2*)&sWT[bc0 + off];
            b0.u2[1] = *(const uint2*)&sWT[bc0 + off + 2];
            b1.u2[0] = *(const uint2*)&sWT[bc0 + 64 * 34 + off];
            b1.u2[1] = *(const uint2*)&sWT[bc0 + 64 * 34 + off + 2];
            b2.u2[0] = *(const uint2*)&sWT[bc0 + 128 * 34 + off];
            b2.u2[1] = *(const uint2*)&sWT[bc0 + 128 * 34 + off + 2];
            acc0 = __builtin_amdgcn_mfma_f32_32x32x16_bf16(afr[ks].v, b0.v, acc0, 0, 0, 0);
            acc1 = __builtin_amdgcn_mfma_f32_32x32x16_bf16(afr[ks].v, b1.v, acc1, 0, 0, 0);
            acc2 = __builtin_amdgcn_mfma_f32_32x32x16_bf16(afr[ks].v, b2.v, acc2, 0, 0, 0);
        }

        __syncthreads();   // (C) scan visible; prior-tile sacc flush done
        int D = sD;
        bool slotmode = (D <= CAPS);
        if (slotmode) {
            for (int p = t; p < D * 256; p += TPB) sacc[p] = 0.f;
        }
        __syncthreads();   // (D) sacc zeroed before atomics

        // ---- epilogue: 16 rows/lane, run-accumulate, 4 atomics per run ----
        float a_s = 0.f, a_v0 = 0.f, a_v1 = 0.f, a_v2 = 0.f;
        int runi = -1, runslot = -1;
        auto flush = [&]() {
            if (runi < 0) return;
            if (slotmode) {
                float* sa = &sacc[runslot * 256];
                atomicAdd(&sa[h], a_s);
                atomicAdd(&sa[64 + h], a_v0);
                atomicAdd(&sa[128 + h], a_v1);
                atomicAdd(&sa[192 + h], a_v2);
            } else {
                atomicAdd(&dscal[(size_t)runi * 64 + h], a_s);
                atomicAdd(&dvec[(size_t)runi * 192 + h], a_v0);
                atomicAdd(&dvec[(size_t)runi * 192 + 64 + h], a_v1);
                atomicAdd(&dvec[(size_t)runi * 192 + 128 + h], a_v2);
            }
        };
#pragma unroll
        for (int r = 0; r < 16; ++r) {
            int el = eh * 32 + (r & 3) + 8 * (r >> 2) + 4 * hi;
            int rg = e0 + el;
            if (rg < E) {
                int i = sii[el];
                int j = jj_s[rg];                       // broadcast load
                if (i != runi) {
                    flush();
                    a_s = 0.f; a_v0 = 0.f; a_v1 = 0.f; a_v2 = 0.f;
                    runi = i; runslot = sslot[el];
                }
                const float4* gp = (const float4*)(geom_s + (size_t)rg * 8);
                float4 g0 = gp[0];
                float4 g1 = gp[1];
                float u0 = bi[0], u1 = bi[1], u2 = bi[2];
                float gg[8] = {g0.x, g0.y, g0.z, g0.w, g1.x, g1.y, g1.z, g1.w};
#pragma unroll
                for (int c = 0; c < 8; ++c) {
                    u0 = fmaf(gg[c], wv_inv[c][0], u0);
                    u1 = fmaf(gg[c], wv_inv[c][1], u1);
                    u2 = fmaf(gg[c], wv_inv[c][2], u2);
                }
                float gate[3];
                float uu[3] = {u0, u1, u2};
#pragma unroll
                for (int q = 0; q < 3; ++q) {
                    float u = uu[q];
                    float sig = 1.0f / (1.0f + __expf(-u));
                    float v = u * sig * (1.0f / 0.6f);
                    v = fminf(fmaxf(v, -20.f), 20.f);
                    float e2v = __expf(2.0f * v);
                    gate[q] = (e2v - 1.0f) / (e2v + 1.0f);
                }
                size_t jb = (size_t)j * 192;
                unsigned w0 = gat[jb + h];
                unsigned w1 = gat[jb + 64 + h];
                unsigned w2 = gat[jb + 128 + h];
                float sp0 = bf16_lo(w0), sp1 = bf16_hi(w0), sp2 = bf16_lo(w1);
                float nv0 = bf16_hi(w1), nv1 = bf16_lo(w2), nv2 = bf16_hi(w2);
                float x1 = sp0 * (acc0[r] + be[0]) * (1.0f + gate[0]) * inv_sqrt3;
                float x2 = sp1 * (acc1[r] + be[1]) * (1.0f + gate[1]) * inv_sqrt3;
                float x3 = sp2 * (acc2[r] + be[2]) * (1.0f + gate[2]) * inv_sqrt3;
                a_s += x3;
                float ud0 = ud_s[3 * rg + 0];
                float ud1 = ud_s[3 * rg + 1];
                float ud2 = ud_s[3 * rg + 2];
                a_v0 += (x1 * nv0 + x2 * ud0) * inv_sqrt_h;
                a_v1 += (x1 * nv1 + x2 * ud1) * inv_sqrt_h;
                a_v2 += (x1 * nv2 + x2 * ud2) * inv_sqrt_h;
            }
        }
        flush();
        __syncthreads();   // (E) all LDS atomics done

        // ---- flush slots: interior = plain store, boundary = atomic ----
        if (slotmode) {
            int Dreal = D - ((sii[63] < 0) ? 1 : 0);
            for (int s = 0; s < D; ++s) {
                int n = sii[sfirst[s]];
                if (n < 0) continue;
                float val = sacc[s * 256 + t];
                bool boundary = (s == 0) || (s == Dreal - 1);
                float* ptr = (t < 64) ? &dscal[(size_t)n * 64 + t]
                                      : &dvec[(size_t)n * 192 + (t - 64)];
                if (boundary) atomicAdd(ptr, val);
                else *ptr = val;
            }
        }
    }
}

// ---------------------------------------------------------------------------
extern "C" void kernel_launch(void* const* d_in, const int* in_sizes, int n_in,
                              void* d_out, int out_size, void* d_ws, size_t ws_size,
                              hipStream_t stream) {
    const float* node_scalar = (const float*)d_in[0];
    const float* node_vector = (const float*)d_in[1];
    const float* edge_rbf    = (const float*)d_in[2];
    const float* edge_udiff  = (const float*)d_in[3];
    const int*   edge_index  = (const int*)d_in[4];
    const float* W_edge      = (const float*)d_in[5];
    const float* b_edge      = (const float*)d_in[6];
    const float* W_x1        = (const float*)d_in[7];
    const float* b_x1        = (const float*)d_in[8];
    const float* W_x2        = (const float*)d_in[9];
    const float* b_x2        = (const float*)d_in[10];
    const float* ln_g        = (const float*)d_in[11];
    const float* ln_b        = (const float*)d_in[12];
    const float* W_inv       = (const float*)d_in[13];
    const float* b_inv       = (const float*)d_in[14];

    int N = in_sizes[0] / 64;
    int E = in_sizes[3] / 3;

    float* ws = (float*)d_ws;
    size_t o = 0;
    auto A4 = [&]() { o = (o + 3) & ~(size_t)3; };
    int*      icnt   = (int*)(ws + o); o += N; A4();
    int*      offs   = (int*)(ws + o); o += N; A4();
    int*      cursor = (int*)(ws + o); o += N; A4();
    int*      bsum   = (int*)(ws + o); o += 1024; A4();
    float*    ref_vec= ws + o; o += (size_t)N * 3; A4();
    unsigned* gat    = (unsigned*)(ws + o); o += (size_t)N * 192; A4();
    int*      perm   = (int*)(ws + o); o += E; A4();
    float*    geom_s = ws + o; o += (size_t)E * 8; A4();
    float*    ud_s   = ws + o; o += (size_t)E * 3; A4();
    int*      ii_s   = (int*)(ws + o); o += E; A4();
    int*      jj_s   = (int*)(ws + o); o += E; A4();

    float* dscal = (float*)d_out;                       // N*64
    float* dvec  = (float*)d_out + (size_t)N * 64;      // N*192

    hipMemsetAsync(icnt, 0, (size_t)N * sizeof(int), stream);
    hipMemsetAsync(d_out, 0, (size_t)out_size * sizeof(float), stream);

    int nb = (N + SCB - 1) / SCB;

    k_hist<<<(E + TPB - 1) / TPB, TPB, 0, stream>>>(edge_index, icnt, E);
    k_scan1<<<nb, SCB, 0, stream>>>(icnt, offs, bsum, N);
    k_scan2<<<1, 1024, 0, stream>>>(bsum, nb);
    k_scan3<<<nb, SCB, 0, stream>>>(offs, bsum, cursor, N);
    k_perm<<<(E + TPB - 1) / TPB, TPB, 0, stream>>>(edge_udiff, edge_index, cursor,
                                                    perm, ii_s, jj_s, ud_s, E);
    k_node_ref<<<(N + TPB - 1) / TPB, TPB, 0, stream>>>(offs, icnt, ud_s, ref_vec, N);
    k_sprojv<<<512, TPB, 0, stream>>>(node_scalar, W_x1, b_x1, W_x2, b_x2,
                                      node_vector, gat, N);
    k_geom_s<<<(E + TPB - 1) / TPB, TPB, 0, stream>>>(ud_s, ii_s, ref_vec,
                                                      ln_g, ln_b, geom_s, E);
    k_main<<<1024, TPB, 0, stream>>>(edge_rbf, W_edge, b_edge, W_inv, b_inv, geom_s,
                                     gat, ud_s, ii_s, jj_s, perm, dscal, dvec, E);
}